// Round 4
// baseline (989.297 us; speedup 1.0000x reference)
//
#include <hip/hip_runtime.h>
#include <math.h>

typedef unsigned long long u64;
typedef unsigned int u32;

#define Hh 960
#define Ww 1280
#define Bb 2
#define Kk 1024
#define Pp 256
#define KP1 1025
#define NSEG 4
#define LISTCAP 131072
#define PR 28
#define PS 57
#define FTS 48
#define FPAD 49

static const size_t HWp = (size_t)Hh * Ww;   // one plane
static const size_t PLn = HWp * Bb;          // B planes

#define TAUf 0.2f
#define NMS_EPS 1e-7f
#define DET_T 0.001f
#define NORMV (-7.6246189861593985f)   /* -log(2*K) */
#define LOGKV (6.9314718055994531f)    /* log(K) */

__constant__ float WR[6] = {1.0f, 1.0f/9.0f, 1.0f/25.0f, 1.0f/49.0f, 1.0f/81.0f, 1.0f/121.0f};

__device__ __forceinline__ int imin(int a,int b){return a<b?a:b;}
__device__ __forceinline__ int imax(int a,int b){return a>b?a:b;}

// ---------------- fused: 3 FED diffusion steps + Hessian response ----------------
// Tile 32x32 output, halo 8 (2 per FED step x3 + 2 for response). Identical
// per-step arithmetic to the reference; out-of-image cells hold 0 at every step
// (zero-pad invariant for Sobel); flux shifts use clamped tile-local indices.
__global__ __launch_bounds__(256) void fed3_resp(const float* __restrict__ src, float* __restrict__ dstL,
                                                 float* __restrict__ resp, int first){
  __shared__ float Abuf[FTS][FPAD], Bbuf[FTS][FPAD], Gbuf[FTS][FPAD];
  const int bx=blockIdx.x*32, by=blockIdx.y*32, b=blockIdx.z;
  const int gx0=bx-8, gy0=by-8;
  const float* S=src+(size_t)b*HWp;
  float* DL=dstL+(size_t)b*HWp;
  float* R=resp+(size_t)b*HWp;
  const int t=threadIdx.x;
  const float k2=(float)(0.05*0.05);
  for(int i=t;i<FTS*FTS;i+=256){
    int ly=i/FTS, lx=i-ly*FTS;
    int gy=gy0+ly, gx=gx0+lx;
    Abuf[ly][lx]=(gy>=0&&gy<Hh&&gx>=0&&gx<Ww)?S[(size_t)gy*Ww+gx]:0.0f;
  }
  __syncthreads();
  float (*cur)[FPAD]=Abuf; float (*nxt)[FPAD]=Bbuf;
  for(int s=0;s<3;++s){
    const int o=2*s;
    // g = 1/(1+(Lx^2+Ly^2)/k^2) on [o+1, FTS-o-1)
    for(int i=t;i<FTS*FTS;i+=256){
      int ly=i/FTS, lx=i-ly*FTS;
      if(ly<o+1||ly>=FTS-o-1||lx<o+1||lx>=FTS-o-1) continue;
      float sx=(-cur[ly-1][lx-1]+cur[ly-1][lx+1]
                -2.0f*cur[ly][lx-1]+2.0f*cur[ly][lx+1]
                -cur[ly+1][lx-1]+cur[ly+1][lx+1])*0.125f;
      float sy=(-cur[ly-1][lx-1]-2.0f*cur[ly-1][lx]-cur[ly-1][lx+1]
                +cur[ly+1][lx-1]+2.0f*cur[ly+1][lx]+cur[ly+1][lx+1])*0.125f;
      Gbuf[ly][lx]=1.0f/(1.0f+(sx*sx+sy*sy)/k2);
    }
    __syncthreads();
    // L' = L + tau*flux on [o+2, FTS-o-2); out-of-image cells stay 0
    for(int i=t;i<FTS*FTS;i+=256){
      int ly=i/FTS, lx=i-ly*FTS;
      if(ly<o+2||ly>=FTS-o-2||lx<o+2||lx>=FTS-o-2) continue;
      int gy=gy0+ly, gx=gx0+lx;
      float v=0.0f;
      if(gy>=0&&gy<Hh&&gx>=0&&gx<Ww){
        int lyn=imax(gy-1,0)-gy0, lys=imin(gy+1,Hh-1)-gy0;
        int lxw=imax(gx-1,0)-gx0, lxe=imin(gx+1,Ww-1)-gx0;
        float Lc=cur[ly][lx];
        float Ln=cur[lyn][lx], Ls=cur[lys][lx], Lw=cur[ly][lxw], Le=cur[ly][lxe];
        float gc=Gbuf[ly][lx], gn=Gbuf[lyn][lx], gs=Gbuf[lys][lx], gw=Gbuf[ly][lxw], ge=Gbuf[ly][lxe];
        float flux=0.5f*((gc+gn)*(Ln-Lc)+(gc+gs)*(Ls-Lc)+(gc+gw)*(Lw-Lc)+(gc+ge)*(Le-Lc));
        v=Lc+TAUf*flux;
      }
      nxt[ly][lx]=v;
    }
    __syncthreads();
    float (*tp)[FPAD]=cur; cur=nxt; nxt=tp;
  }
  // cur = final L, valid on [6,42). Write 32x32 core out.
  for(int i=t;i<32*32;i+=256){
    int oy=i>>5, ox=i&31;
    DL[(size_t)(by+oy)*Ww+(bx+ox)]=cur[8+oy][8+ox];
  }
  // Sx = sobel_x(L) on [7,41), zero outside image (zero-pad of conv output)
  for(int i=t;i<FTS*FTS;i+=256){
    int ly=i/FTS, lx=i-ly*FTS;
    if(ly<7||ly>=41||lx<7||lx>=41) continue;
    int gy=gy0+ly, gx=gx0+lx;
    float v=0.0f;
    if(gy>=0&&gy<Hh&&gx>=0&&gx<Ww){
      v=(-cur[ly-1][lx-1]+cur[ly-1][lx+1]
         -2.0f*cur[ly][lx-1]+2.0f*cur[ly][lx+1]
         -cur[ly+1][lx-1]+cur[ly+1][lx+1])*0.125f;
    }
    Gbuf[ly][lx]=v;
  }
  __syncthreads();
  // det = Lxx*Lyy - Lxy^2 on the 32x32 core
  for(int i=t;i<32*32;i+=256){
    int oy=i>>5, ox=i&31;
    int ly=8+oy, lx=8+ox;
    float Lxx=cur[ly][lx-1]-2.0f*cur[ly][lx]+cur[ly][lx+1];
    float Lyy=cur[ly-1][lx]-2.0f*cur[ly][lx]+cur[ly+1][lx];
    float Lxy=(-Gbuf[ly-1][lx-1]-2.0f*Gbuf[ly-1][lx]-Gbuf[ly-1][lx+1]
               +Gbuf[ly+1][lx-1]+2.0f*Gbuf[ly+1][lx]+Gbuf[ly+1][lx+1])*0.125f;
    float det=Lxx*Lyy-Lxy*Lxy;
    size_t id=(size_t)(by+oy)*Ww+(bx+ox);
    R[id]=first?fmaxf(det,0.0f):fmaxf(R[id],det);
  }
}

// ---------------- fused: threshold + 5x5 NMS + 7x7 NMS + block compaction ----------------
__global__ __launch_bounds__(256) void detect_compact(const float* __restrict__ resp,
                                                      u64* __restrict__ lists,
                                                      int* __restrict__ cnt, int segbase){
  const int TS=42;                 // 32 + 2*5 halo (3 for 7x7 + 2 for the 5x5 mask in the halo)
  __shared__ float Tt[TS][TS+1];   // thresholded response
  __shared__ float Ss[38][39];     // 5x5-NMS-masked, halo 3
  __shared__ u64 keys[1024];
  __shared__ int lcnt, gbase;
  const int bx = blockIdx.x*32, by = blockIdx.y*32, b = blockIdx.z;
  const float* S = resp + (size_t)b*HWp;
  const int t = threadIdx.y*32 + threadIdx.x;
  if (t==0) lcnt=0;
  for (int i=t;i<TS*TS;i+=256){
    int ly=i/TS, lx=i-ly*TS;
    int gy=by+ly-5, gx=bx+lx-5;
    float v = (gy>=0 && gy<Hh && gx>=0 && gx<Ww) ? S[(size_t)gy*Ww+gx] : 0.0f;
    Tt[ly][lx] = (v>DET_T) ? v : 0.0f;
  }
  __syncthreads();
  for (int i=t;i<38*38;i+=256){
    int ly=i/38, lx=i-ly*38;
    int ty=ly+2, tx=lx+2;
    float m=0.0f;
    #pragma unroll
    for(int dy=-2;dy<=2;dy++)
      #pragma unroll
      for(int dx=-2;dx<=2;dx++)
        m=fmaxf(m,Tt[ty+dy][tx+dx]);
    float c=Tt[ty][tx];
    Ss[ly][lx]=(c>=m-NMS_EPS)?c:0.0f;
  }
  __syncthreads();
  const int seg=segbase+b;
  for (int r=0;r<4;++r){
    int oy=threadIdx.y + r*8, ox=threadIdx.x;
    int gy=by+oy, gx=bx+ox;
    bool pos=false; u64 key=0;
    if (gy<Hh && gx<Ww){
      float v=Ss[oy+3][ox+3];
      if (v>0.0f){
        float m=0.0f;
        #pragma unroll
        for(int dy=0;dy<7;dy++)
          #pragma unroll
          for(int dx=0;dx<7;dx++)
            m=fmaxf(m,Ss[oy+dy][ox+dx]);
        if (v>=m-NMS_EPS){
          u32 idx=(u32)(gy*Ww+gx);
          key=((u64)__float_as_uint(v)<<32)|(u64)(0xFFFFFFFFu-idx);  // value desc, index asc
          pos=true;
        }
      }
    }
    u64 mask=__ballot(pos);
    if (mask){
      int lane=t&63;
      int leader=__ffsll((long long)mask)-1;
      int base=0;
      if (lane==leader) base=atomicAdd(&lcnt,__popcll(mask));
      base=__shfl(base,leader);
      if (pos){
        int rk=__popcll(mask & ((1ULL<<lane)-1ULL));
        keys[base+rk]=key;
      }
    }
  }
  __syncthreads();
  if (t==0 && lcnt>0) gbase=atomicAdd(&cnt[seg*64], lcnt);   // one atomic per block
  __syncthreads();
  int n=lcnt;
  for (int i=t;i<n;i+=256){
    int p=gbase+i;
    if (p<LISTCAP) lists[(size_t)seg*LISTCAP+p]=keys[i];
  }
}

// ---------------- radix-select top-K: histogram pass ----------------
__global__ void topk_hist(const u64* __restrict__ lists, const int* __restrict__ cnt,
                          const u64* __restrict__ prefix, const int* __restrict__ takeAll,
                          u32* __restrict__ ghist, int round){
  int seg=blockIdx.y;
  if(round>0 && takeAll[seg]) return;
  __shared__ u32 h[256];
  h[threadIdx.x]=0; __syncthreads();
  int n=imin(cnt[seg*64],LISTCAP);
  int shift=56-8*round;
  u64 maskHi=(round==0)?0ULL:(~0ULL<<(shift+8));
  u64 pfx=prefix[seg];
  for(int i=blockIdx.x*256+threadIdx.x;i<n;i+=gridDim.x*256){
    u64 k=lists[(size_t)seg*LISTCAP+i];
    if((k&maskHi)==pfx) atomicAdd(&h[(int)((k>>shift)&255ULL)],1u);
  }
  __syncthreads();
  if(h[threadIdx.x]) atomicAdd(&ghist[seg*256+threadIdx.x],h[threadIdx.x]);
}

// ---------------- radix-select: decide byte, advance state ----------------
__global__ void topk_decide(u32* __restrict__ ghist, const int* __restrict__ cnt,
                            int* __restrict__ krem, int* __restrict__ takeAll,
                            u64* __restrict__ prefix, u64* __restrict__ Tf, int round){
  int t=threadIdx.x;
  if(t<NSEG){
    int seg=t;
    if(round==0){
      krem[seg]=Kk;
      prefix[seg]=0ULL;
      takeAll[seg]=(imin(cnt[seg*64],LISTCAP)<=Kk)?1:0;
    }
    if(takeAll[seg]){
      if(round==7) Tf[seg]=1ULL;   // all keys >= 1 (value>0 => high bits nonzero)
    } else {
      int kr=krem[seg];
      const u32* h=&ghist[seg*256];
      int acc=0; int b=255;
      for(;b>0;--b){ int c2=(int)h[b]; if(acc+c2>=kr) break; acc+=c2; }
      int shift=56-8*round;
      prefix[seg]|=((u64)(u32)b)<<shift;
      krem[seg]=kr-acc;
      if(round==7) Tf[seg]=prefix[seg];
    }
  }
  __syncthreads();
  for(int i=t;i<NSEG*256;i+=blockDim.x) ghist[i]=0u;  // clear for next round
}

// ---------------- gather keys >= threshold (wave-aggregated atomic) ----------------
__global__ void topk_gather(const u64* __restrict__ lists, const int* __restrict__ cnt,
                            const u64* __restrict__ Tf, u64* __restrict__ selbuf, int* __restrict__ selcnt){
  int seg=blockIdx.y;
  int n=imin(cnt[seg*64],LISTCAP);
  u64 T=Tf[seg];
  for(int i0=blockIdx.x*256;i0<n;i0+=gridDim.x*256){
    int i=i0+threadIdx.x;
    bool sel=false; u64 k=0;
    if(i<n){ k=lists[(size_t)seg*LISTCAP+i]; sel=(k>=T); }
    u64 mask=__ballot(sel);
    if(mask){
      int lane=threadIdx.x&63;
      int leader=__ffsll((long long)mask)-1;
      int base=0;
      if(lane==leader) base=atomicAdd(&selcnt[seg*64],__popcll(mask));
      base=__shfl(base,leader);
      if(sel){
        int p=base+__popcll(mask & ((1ULL<<lane)-1ULL));
        if(p<Kk) selbuf[(size_t)seg*Kk+p]=k;
      }
    }
  }
}

// ---------------- sort 1024 keys desc, emit keypoint meta + k1/k2 ----------------
__global__ __launch_bounds__(1024) void finalize_kernel(const u64* __restrict__ selbuf, const int* __restrict__ selcnt,
                                int* __restrict__ kyi, int* __restrict__ kxi, float* __restrict__ kval,
                                float* __restrict__ outp){
  int seg=blockIdx.x, tid=threadIdx.x;
  __shared__ u64 a[1024];
  int n=selcnt[seg*64]; if(n>Kk)n=Kk;
  a[tid]=(tid<n)?selbuf[(size_t)seg*Kk+tid]:0ULL;
  __syncthreads();
  for(int k=2;k<=1024;k<<=1){
    for(int j=k>>1;j>0;j>>=1){
      int ixj=tid^j;
      if(ixj>tid){
        u64 x=a[tid], y=a[ixj];
        bool desc=((tid&k)==0);
        if(desc ? (x<y) : (x>y)){ a[tid]=y; a[ixj]=x; }
      }
      __syncthreads();
    }
  }
  u64 key=a[tid];
  bool val=(key!=0ULL);
  u32 idx=0xFFFFFFFFu-(u32)(key&0xFFFFFFFFULL);
  int y= val ? (int)(idx/Ww) : 0;
  int x= val ? (int)(idx%Ww) : 0;
  int mi=seg*Kk+tid;
  kyi[mi]=y; kxi[mi]=x; kval[mi]= val?1.0f:0.0f;
  int imi=seg>>1, bb=seg&1;
  float* ko=outp + (size_t)imi*(Bb*Kk*2) + ((size_t)bb*Kk+tid)*2;
  ko[0]= val ? (float)y : -1.0f;
  ko[1]= val ? (float)x : -1.0f;
}

// ---------------- Gaussian weights (1D, normalized) ----------------
__global__ void init_weights(float* wn){
  if(threadIdx.x==0 && blockIdx.x==0){
    double w[15]; double S=0.0;
    for(int i=0;i<15;i++){ double c=(double)i-7.0; w[i]=exp(-(c*c)/(2.0*2.5*2.5)); S+=w[i]; }
    for(int i=0;i<15;i++) wn[i]=(float)(w[i]/S);
  }
}

__device__ __forceinline__ float ldz(const float* __restrict__ img,int y,int x){
  return (y>=0&&y<Hh&&x>=0&&x<Ww)?img[(size_t)y*Ww+x]:0.0f;
}

// ---------------- per-keypoint orientation (15x15 Gaussian-weighted Sobel) ----------------
__global__ __launch_bounds__(64) void orient_kernel(const float* __restrict__ img1, const float* __restrict__ img2,
                              const int* __restrict__ kyi, const int* __restrict__ kxi,
                              const float* __restrict__ wn, float* __restrict__ kth){
  int seg=blockIdx.y, ki=blockIdx.x, lane=threadIdx.x;
  __shared__ float w15[15];
  if(lane<15) w15[lane]=wn[lane];
  __syncthreads();
  const float* img=(seg<2?img1:img2)+(size_t)(seg&1)*HWp;
  int mi=seg*Kk+ki;
  int yc=kyi[mi], xc=kxi[mi];
  float ax=0.0f, ay=0.0f;
  for(int tp=lane;tp<225;tp+=64){
    int du=tp/15-7, dv=tp-(tp/15)*15-7;
    int yy=yc+du, xx=xc+dv;
    if(yy<0||yy>=Hh||xx<0||xx>=Ww) continue;   // zero-pad of Sobel output
    float p00=ldz(img,yy-1,xx-1), p01=ldz(img,yy-1,xx), p02=ldz(img,yy-1,xx+1);
    float p10=ldz(img,yy,xx-1),                          p12=ldz(img,yy,xx+1);
    float p20=ldz(img,yy+1,xx-1), p21=ldz(img,yy+1,xx), p22=ldz(img,yy+1,xx+1);
    float sx=(-p00+p02-2.0f*p10+2.0f*p12-p20+p22)*0.125f;
    float sy=(-p00-2.0f*p01-p02+p20+2.0f*p21+p22)*0.125f;
    float wgt=w15[du+7]*w15[dv+7];
    ax=fmaf(wgt,sx,ax); ay=fmaf(wgt,sy,ay);
  }
  for(int o=32;o;o>>=1){ ax+=__shfl_down(ax,o); ay+=__shfl_down(ay,o); }
  if(lane==0) kth[mi]=atan2f(ay,ax);
}

// ---------------- BAD descriptor: LDS-staged 57x57 patch + box samples + normalize ----------------
__global__ __launch_bounds__(256) void bad_kernel(const float* __restrict__ img1, const float* __restrict__ img2,
                           const float* __restrict__ offs, const float* __restrict__ thrv,
                           const int* __restrict__ rad,
                           const int* __restrict__ kyi, const int* __restrict__ kxi,
                           const float* __restrict__ kval, const float* __restrict__ kth,
                           float* __restrict__ d1, float* __restrict__ d2,
                           float* __restrict__ sq1, float* __restrict__ sq2){
  __shared__ float patch[PS][PS+1];
  __shared__ float sm[4];
  __shared__ float nsh;
  int seg=blockIdx.y, ki=blockIdx.x, p=threadIdx.x;
  const float* img=(seg<2?img1:img2)+(size_t)(seg&1)*HWp;
  int mi=seg*Kk+ki;
  int yci=kyi[mi], xci=kxi[mi];
  // stage the 57x57 neighborhood (zero outside image; "skip" == "+0.0f")
  for (int i=p;i<PS*PS;i+=256){
    int ly=i/PS, lx=i-ly*PS;
    int gy=yci-PR+ly, gx=xci-PR+lx;
    patch[ly][lx]=(gy>=0&&gy<Hh&&gx>=0&&gx<Ww)?img[(size_t)gy*Ww+gx]:0.0f;
  }
  __syncthreads();
  float yc=(float)yci, xc=(float)xci;
  float th=kth[mi];
  float c=cosf(th), s=sinf(th);
  float ox1=offs[p*4+0], oy1=offs[p*4+1], ox2=offs[p*4+2], oy2=offs[p*4+3];
  int r=rad[p];
  float w=WR[r];
  float px1=xc+c*ox1-s*oy1, py1=yc+s*ox1+c*oy1;
  float px2=xc+c*ox2-s*oy2, py2=yc+s*ox2+c*oy2;
  // local boxsum from LDS (same tap order & arithmetic as global version)
  auto boxl=[&](float px,float py,int r_)->float{
    float rx=rintf(px), ry=rintf(py);
    int xi=(int)fminf(fmaxf(rx,0.0f),(float)(Ww-1));
    int yi=(int)fminf(fmaxf(ry,0.0f),(float)(Hh-1));
    int lx=xi-(xci-PR), ly=yi-(yci-PR);   // guaranteed in [5,51]
    float acc=0.0f;
    for(int dy=-r_;dy<=r_;dy++){
      const float* rowp=&patch[ly+dy][lx];
      for(int dx=-r_;dx<=r_;dx++) acc+=rowp[dx];
    }
    return acc;
  };
  float s1=boxl(px1,py1,r)*w;
  float s2=boxl(px2,py2,r)*w;
  float v=(s1-s2-thrv[p])*kval[mi];
  float t=v*v;
  for(int o=32;o;o>>=1) t+=__shfl_down(t,o);
  if((p&63)==0) sm[p>>6]=t;
  __syncthreads();
  if(p==0) nsh=sqrtf(sm[0]+sm[1]+sm[2]+sm[3]);
  __syncthreads();
  float dv=v/(nsh+1e-8f);
  float* dd=(seg<2?d1:d2);
  dd[((size_t)(seg&1)*Kk+ki)*Pp+p]=dv;
  float t2=dv*dv;
  for(int o=32;o;o>>=1) t2+=__shfl_down(t2,o);
  __syncthreads();
  if((p&63)==0) sm[p>>6]=t2;
  __syncthreads();
  if(p==0){ float* sq=(seg<2?sq1:sq2); sq[(size_t)(seg&1)*Kk+ki]=sm[0]+sm[1]+sm[2]+sm[3]; }
}

// ---------------- pairwise distance -> Z (and transposed copy) ----------------
// 64x64 tile, 4x4 register blocking, transposed LDS (float4, conflict-free)
__global__ __launch_bounds__(256) void dist_kernel(const float* __restrict__ d1, const float* __restrict__ d2,
                            const float* __restrict__ sq1, const float* __restrict__ sq2,
                            float* __restrict__ Zm, float* __restrict__ Zt){
  int b=blockIdx.z;
  int i0=blockIdx.y*64, j0=blockIdx.x*64;
  int tid=threadIdx.x;
  int tx=tid&15, ty=tid>>4;
  __shared__ float Ast[64][68], Bst[64][68];   // [k][row], [k][col]
  const float* D1=d1+(size_t)b*Kk*Pp;
  const float* D2=d2+(size_t)b*Kk*Pp;
  float acc[4][4]={};
  for(int p0=0;p0<Pp;p0+=64){
    for(int i=tid;i<64*16;i+=256){
      int row=i>>4, c4=(i&15)<<2;
      float4 va=*reinterpret_cast<const float4*>(&D1[(size_t)(i0+row)*Pp+p0+c4]);
      float4 vb=*reinterpret_cast<const float4*>(&D2[(size_t)(j0+row)*Pp+p0+c4]);
      Ast[c4+0][row]=va.x; Ast[c4+1][row]=va.y; Ast[c4+2][row]=va.z; Ast[c4+3][row]=va.w;
      Bst[c4+0][row]=vb.x; Bst[c4+1][row]=vb.y; Bst[c4+2][row]=vb.z; Bst[c4+3][row]=vb.w;
    }
    __syncthreads();
    #pragma unroll 8
    for(int kk=0;kk<64;++kk){
      float4 av=*reinterpret_cast<const float4*>(&Ast[kk][ty*4]);
      float4 bv=*reinterpret_cast<const float4*>(&Bst[kk][tx*4]);
      acc[0][0]=fmaf(av.x,bv.x,acc[0][0]); acc[0][1]=fmaf(av.x,bv.y,acc[0][1]);
      acc[0][2]=fmaf(av.x,bv.z,acc[0][2]); acc[0][3]=fmaf(av.x,bv.w,acc[0][3]);
      acc[1][0]=fmaf(av.y,bv.x,acc[1][0]); acc[1][1]=fmaf(av.y,bv.y,acc[1][1]);
      acc[1][2]=fmaf(av.y,bv.z,acc[1][2]); acc[1][3]=fmaf(av.y,bv.w,acc[1][3]);
      acc[2][0]=fmaf(av.z,bv.x,acc[2][0]); acc[2][1]=fmaf(av.z,bv.y,acc[2][1]);
      acc[2][2]=fmaf(av.z,bv.z,acc[2][2]); acc[2][3]=fmaf(av.z,bv.w,acc[2][3]);
      acc[3][0]=fmaf(av.w,bv.x,acc[3][0]); acc[3][1]=fmaf(av.w,bv.y,acc[3][1]);
      acc[3][2]=fmaf(av.w,bv.z,acc[3][2]); acc[3][3]=fmaf(av.w,bv.w,acc[3][3]);
    }
    __syncthreads();
  }
  int gi=i0+ty*4, gj=j0+tx*4;
  float si[4], sj[4];
  #pragma unroll
  for(int i=0;i<4;i++){ si[i]=sq1[b*Kk+gi+i]; sj[i]=sq2[b*Kk+gj+i]; }
  #pragma unroll
  for(int i=0;i<4;i++){
    #pragma unroll
    for(int j=0;j<4;j++){
      float dd=si[i]+sj[j]-2.0f*acc[i][j];
      float dist=sqrtf(fmaxf(dd,0.0f)+1e-12f);
      Zm[((size_t)b*KP1+(gi+i))*KP1+(gj+j)]=-dist;
      Zt[((size_t)b*KP1+(gj+j))*KP1+(gi+i)]=-dist;
    }
  }
}

__global__ void zborder_kernel(float* __restrict__ Zm, float* __restrict__ Zt){
  int i=blockIdx.x*256+threadIdx.x;
  if(i>=Bb*KP1) return;
  int b=i/KP1, j=i-(i/KP1)*KP1;
  Zm[((size_t)b*KP1+j)*KP1+Kk]=1.0f;
  Zm[((size_t)b*KP1+Kk)*KP1+j]=1.0f;
  Zt[((size_t)b*KP1+j)*KP1+Kk]=1.0f;
  Zt[((size_t)b*KP1+Kk)*KP1+j]=1.0f;
}

// ---------------- Sinkhorn half-iteration: res = log_mu - log sum exp(Z[i,:]+o[:]) ----------------
// One wave per row; single pass (arguments bounded, no overflow; differs from
// max-stabilized form by ~1ulp). 4 rows per block, no LDS, no barriers.
__global__ __launch_bounds__(256) void sink_lse(const float* __restrict__ Zm, const float* __restrict__ ov,
                                                float* __restrict__ res){
  int row=blockIdx.x*4+(threadIdx.x>>6);
  if(row>=Bb*KP1) return;
  int b=row/KP1, i=row-b*KP1;
  int lane=threadIdx.x&63;
  const float* rp=Zm+((size_t)b*KP1+i)*KP1;
  const float* o=ov+(size_t)b*KP1;
  float s=0.0f;
  for(int j=lane;j<KP1;j+=64) s+=expf(rp[j]+o[j]);
  for(int off=32;off;off>>=1) s+=__shfl_down(s,off);
  if(lane==0){
    float lm=(i<Kk)?NORMV:(LOGKV+NORMV);
    res[(size_t)b*KP1+i]=lm-logf(s);
  }
}

// ---------------- final probs = exp(Z+u+v-norm) ----------------
__global__ void probs_kernel(const float* __restrict__ Zm, const float* __restrict__ uu,
                             const float* __restrict__ vv, float* __restrict__ outp){
  size_t i=(size_t)blockIdx.x*256+threadIdx.x;
  const size_t tot=(size_t)Bb*KP1*KP1;
  if(i>=tot) return;
  size_t b=i/((size_t)KP1*KP1);
  size_t rem=i-b*(size_t)KP1*KP1;
  int rr=(int)(rem/KP1), cc=(int)(rem-(size_t)(rem/KP1)*KP1);
  outp[i]=expf(Zm[i]+uu[b*KP1+rr]+vv[b*KP1+cc]-NORMV);
}

extern "C" void kernel_launch(void* const* d_in, const int* in_sizes, int n_in,
                              void* d_out, int out_size, void* d_ws, size_t ws_size,
                              hipStream_t stream) {
  (void)in_sizes; (void)n_in; (void)out_size; (void)ws_size;
  const float* img1=(const float*)d_in[0];
  const float* img2=(const float*)d_in[1];
  const float* offs=(const float*)d_in[2];
  const float* thrv=(const float*)d_in[3];
  const int*   rad =(const int*)d_in[4];
  float* out=(float*)d_out;

  char* wp=(char*)d_ws;
  auto carve=[&](size_t bytes)->char*{ char* p=wp; wp += (bytes+255)&~(size_t)255; return p; };
  float* r0  =(float*)carve(PLn*4);            // L ping / Z
  float* r1  =(float*)carve(PLn*4);            // L pong / Zt
  float* resp=(float*)carve(PLn*4);
  u64*  lists=(u64*)carve((size_t)NSEG*LISTCAP*8);
  char* stateblk = carve(8192);
  int* cnt     =(int*)(stateblk);              // [seg*64], 256B stride per seg
  int* selcnt  =(int*)(stateblk+1024);         // [seg*64]
  int* krem    =(int*)(stateblk+2048);
  int* takeAll =(int*)(stateblk+2112);
  u64* prefix  =(u64*)(stateblk+2176);
  u64* Tf      =(u64*)(stateblk+2240);
  u32* ghist   =(u32*)(stateblk+2304);         // 4KB
  u64* selbuf  =(u64*)carve((size_t)NSEG*Kk*8);
  int* kyi     =(int*)carve((size_t)NSEG*Kk*4);
  int* kxi     =(int*)carve((size_t)NSEG*Kk*4);
  float* kval  =(float*)carve((size_t)NSEG*Kk*4);
  float* kth   =(float*)carve((size_t)NSEG*Kk*4);
  float* d1    =(float*)carve((size_t)Bb*Kk*Pp*4);
  float* d2    =(float*)carve((size_t)Bb*Kk*Pp*4);
  float* sq1   =(float*)carve((size_t)Bb*Kk*4);
  float* sq2   =(float*)carve((size_t)Bb*Kk*4);
  float* uvec  =(float*)carve((size_t)Bb*KP1*4);
  float* vvec  =(float*)carve((size_t)Bb*KP1*4);
  float* wn    =(float*)carve(64);

  hipMemsetAsync(stateblk, 0, 8192, stream);
  init_weights<<<1,32,0,stream>>>(wn);

  dim3 FG(Ww/32, Hh/32, Bb);
  dim3 TG(Ww/32, Hh/32, Bb), TB(32,8);
  for(int im=0; im<2; ++im){
    const float* srcimg = (im==0)? img1 : img2;
    // 3 scales: (3 FED steps + response) fused per launch
    fed3_resp<<<FG,dim3(256),0,stream>>>(srcimg, r1, resp, 1);
    fed3_resp<<<FG,dim3(256),0,stream>>>(r1, r0, resp, 0);
    fed3_resp<<<FG,dim3(256),0,stream>>>(r0, r1, resp, 0);
    detect_compact<<<TG,TB,0,stream>>>(resp, lists, cnt, im*2);
  }

  for(int rd=0; rd<8; ++rd){
    topk_hist<<<dim3(32,NSEG),dim3(256),0,stream>>>(lists, cnt, prefix, takeAll, ghist, rd);
    topk_decide<<<1,256,0,stream>>>(ghist, cnt, krem, takeAll, prefix, Tf, rd);
  }
  topk_gather<<<dim3(64,NSEG),dim3(256),0,stream>>>(lists, cnt, Tf, selbuf, selcnt);
  finalize_kernel<<<NSEG,1024,0,stream>>>(selbuf, selcnt, kyi, kxi, kval, out);
  orient_kernel<<<dim3(Kk,NSEG),dim3(64),0,stream>>>(img1, img2, kyi, kxi, wn, kth);
  bad_kernel<<<dim3(Kk,NSEG),dim3(256),0,stream>>>(img1, img2, offs, thrv, rad,
                                                   kyi, kxi, kval, kth, d1, d2, sq1, sq2);

  float* Zm=r0; float* Zt=r1;   // reuse image buffers
  dist_kernel<<<dim3(16,16,Bb),dim3(256),0,stream>>>(d1,d2,sq1,sq2,Zm,Zt);
  zborder_kernel<<<dim3((Bb*KP1+255)/256),dim3(256),0,stream>>>(Zm,Zt);
  hipMemsetAsync(uvec,0,(size_t)Bb*KP1*4,stream);
  hipMemsetAsync(vvec,0,(size_t)Bb*KP1*4,stream);
  for(int it=0; it<20; ++it){
    sink_lse<<<dim3((Bb*KP1+3)/4),dim3(256),0,stream>>>(Zm, vvec, uvec);
    sink_lse<<<dim3((Bb*KP1+3)/4),dim3(256),0,stream>>>(Zt, uvec, vvec);
  }
  size_t tot=(size_t)Bb*KP1*KP1;
  probs_kernel<<<dim3((u32)((tot+255)/256)),dim3(256),0,stream>>>(Zm, uvec, vvec, out + (size_t)2*Bb*Kk*2);
}

// Round 5
// 836.713 us; speedup vs baseline: 1.1824x; 1.1824x over previous
//
#include <hip/hip_runtime.h>
#include <math.h>

typedef unsigned long long u64;
typedef unsigned int u32;

#define Hh 960
#define Ww 1280
#define Bb 2
#define Kk 1024
#define Pp 256
#define KP1 1025
#define NSEG 4
#define LISTCAP 131072
#define PR 28
#define PS 57
#define ZLD 1040                         /* padded Z row stride (16B-aligned) */
static const size_t ZB = (size_t)KP1*ZLD;  // per-batch Z floats

static const size_t HWp = (size_t)Hh * Ww;   // one plane
static const size_t PLn = HWp * Bb;          // B planes

#define TAUf 0.2f
#define NMS_EPS 1e-7f
#define DET_T 0.001f
#define NORMV (-7.6246189861593985f)   /* -log(2*K) */
#define LOGKV (6.9314718055994531f)    /* log(K) */

__constant__ float WR[6] = {1.0f, 1.0f/9.0f, 1.0f/25.0f, 1.0f/49.0f, 1.0f/81.0f, 1.0f/121.0f};

__device__ __forceinline__ int imin(int a,int b){return a<b?a:b;}
__device__ __forceinline__ int imax(int a,int b){return a>b?a:b;}

// ---------------- FED diffusion step (fused: Sobel->g->flux) ----------------
__global__ __launch_bounds__(256) void fed_step(const float* __restrict__ src, float* __restrict__ dst){
  __shared__ float Lt[36][37];
  __shared__ float Gt[34][35];
  const int bx = blockIdx.x*32, by = blockIdx.y*32, b = blockIdx.z;
  const float* S = src + (size_t)b*HWp;
  float* D = dst + (size_t)b*HWp;
  const int t = threadIdx.y*32 + threadIdx.x;
  for (int i=t;i<36*36;i+=256){
    int ly=i/36, lx=i-ly*36;
    int gy=by+ly-2, gx=bx+lx-2;
    Lt[ly][lx] = (gy>=0 && gy<Hh && gx>=0 && gx<Ww) ? S[(size_t)gy*Ww+gx] : 0.0f;  // zero-pad for Sobel
  }
  __syncthreads();
  const float k2 = (float)(0.05*0.05);
  for (int i=t;i<34*34;i+=256){
    int ly=i/34, lx=i-ly*34;
    int Ly=ly+1, Lx=lx+1;
    float sx = (-Lt[Ly-1][Lx-1]+Lt[Ly-1][Lx+1]
                -2.0f*Lt[Ly][Lx-1]+2.0f*Lt[Ly][Lx+1]
                -Lt[Ly+1][Lx-1]+Lt[Ly+1][Lx+1])*0.125f;
    float sy = (-Lt[Ly-1][Lx-1]-2.0f*Lt[Ly-1][Lx]-Lt[Ly-1][Lx+1]
                +Lt[Ly+1][Lx-1]+2.0f*Lt[Ly+1][Lx]+Lt[Ly+1][Lx+1])*0.125f;
    Gt[ly][lx] = 1.0f/(1.0f + (sx*sx+sy*sy)/k2);
  }
  __syncthreads();
  for (int r=0;r<4;++r){
    int oy=threadIdx.y + r*8, ox=threadIdx.x;
    int gy=by+oy, gx=bx+ox;
    if (gy>=Hh || gx>=Ww) continue;
    // edge-clamped neighbor coordinates (matches np.pad 'edge')
    int gyn=imax(gy-1,0), gys=imin(gy+1,Hh-1), gxw=imax(gx-1,0), gxe=imin(gx+1,Ww-1);
    float Lc=Lt[oy+2][ox+2];
    float Ln=Lt[gyn-by+2][ox+2];
    float Ls=Lt[gys-by+2][ox+2];
    float Lw=Lt[oy+2][gxw-bx+2];
    float Le=Lt[oy+2][gxe-bx+2];
    float gc=Gt[oy+1][ox+1];
    float gn=Gt[gyn-by+1][ox+1];
    float gs=Gt[gys-by+1][ox+1];
    float gw=Gt[oy+1][gxw-bx+1];
    float ge=Gt[oy+1][gxe-bx+1];
    float flux = 0.5f*((gc+gn)*(Ln-Lc) + (gc+gs)*(Ls-Lc) + (gc+gw)*(Lw-Lc) + (gc+ge)*(Le-Lc));
    D[(size_t)gy*Ww+gx] = Lc + TAUf*flux;
  }
}

// ---------------- Hessian response (Lxx*Lyy - Lxy^2), resp = max(resp, det) ----------------
__global__ __launch_bounds__(256) void response_kernel(const float* __restrict__ src, float* __restrict__ resp){
  __shared__ float Lt[36][37];
  __shared__ float Sx[34][35];
  const int bx = blockIdx.x*32, by = blockIdx.y*32, b = blockIdx.z;
  const float* S = src + (size_t)b*HWp;
  float* R = resp + (size_t)b*HWp;
  const int t = threadIdx.y*32 + threadIdx.x;
  for (int i=t;i<36*36;i+=256){
    int ly=i/36, lx=i-ly*36;
    int gy=by+ly-2, gx=bx+lx-2;
    Lt[ly][lx] = (gy>=0 && gy<Hh && gx>=0 && gx<Ww) ? S[(size_t)gy*Ww+gx] : 0.0f;
  }
  __syncthreads();
  for (int i=t;i<34*34;i+=256){
    int ly=i/34, lx=i-ly*34;
    int gy=by+ly-1, gx=bx+lx-1;
    float v=0.0f;
    if (gy>=0 && gy<Hh && gx>=0 && gx<Ww){   // Sx is zero outside image (zero-pad of first conv's output)
      int Ly=ly+1, Lx=lx+1;
      v = (-Lt[Ly-1][Lx-1]+Lt[Ly-1][Lx+1]
           -2.0f*Lt[Ly][Lx-1]+2.0f*Lt[Ly][Lx+1]
           -Lt[Ly+1][Lx-1]+Lt[Ly+1][Lx+1])*0.125f;
    }
    Sx[ly][lx]=v;
  }
  __syncthreads();
  for (int r=0;r<4;++r){
    int oy=threadIdx.y + r*8, ox=threadIdx.x;
    int gy=by+oy, gx=bx+ox;
    if (gy>=Hh || gx>=Ww) continue;
    int Ly=oy+2, Lx=ox+2;
    float Lxx = Lt[Ly][Lx-1]-2.0f*Lt[Ly][Lx]+Lt[Ly][Lx+1];
    float Lyy = Lt[Ly-1][Lx]-2.0f*Lt[Ly][Lx]+Lt[Ly+1][Lx];
    int Sy=oy+1, Sxi=ox+1;
    float Lxy = (-Sx[Sy-1][Sxi-1]-2.0f*Sx[Sy-1][Sxi]-Sx[Sy-1][Sxi+1]
                 +Sx[Sy+1][Sxi-1]+2.0f*Sx[Sy+1][Sxi]+Sx[Sy+1][Sxi+1])*0.125f;
    float det = Lxx*Lyy - Lxy*Lxy;
    size_t id=(size_t)gy*Ww+gx;
    R[id] = fmaxf(R[id], det);
  }
}

// ---------------- fused: threshold + 5x5 NMS + 7x7 NMS + block compaction ----------------
__global__ __launch_bounds__(256) void detect_compact(const float* __restrict__ resp,
                                                      u64* __restrict__ lists,
                                                      int* __restrict__ cnt, int segbase){
  const int TS=42;                 // 32 + 2*5 halo (3 for 7x7 + 2 for the 5x5 mask in the halo)
  __shared__ float Tt[TS][TS+1];   // thresholded response
  __shared__ float Ss[38][39];     // 5x5-NMS-masked, halo 3
  __shared__ u64 keys[1024];
  __shared__ int lcnt, gbase;
  const int bx = blockIdx.x*32, by = blockIdx.y*32, b = blockIdx.z;
  const float* S = resp + (size_t)b*HWp;
  const int t = threadIdx.y*32 + threadIdx.x;
  if (t==0) lcnt=0;
  for (int i=t;i<TS*TS;i+=256){
    int ly=i/TS, lx=i-ly*TS;
    int gy=by+ly-5, gx=bx+lx-5;
    float v = (gy>=0 && gy<Hh && gx>=0 && gx<Ww) ? S[(size_t)gy*Ww+gx] : 0.0f;
    Tt[ly][lx] = (v>DET_T) ? v : 0.0f;
  }
  __syncthreads();
  for (int i=t;i<38*38;i+=256){
    int ly=i/38, lx=i-ly*38;
    int ty=ly+2, tx=lx+2;
    float m=0.0f;
    #pragma unroll
    for(int dy=-2;dy<=2;dy++)
      #pragma unroll
      for(int dx=-2;dx<=2;dx++)
        m=fmaxf(m,Tt[ty+dy][tx+dx]);
    float c=Tt[ty][tx];
    Ss[ly][lx]=(c>=m-NMS_EPS)?c:0.0f;
  }
  __syncthreads();
  const int seg=segbase+b;
  for (int r=0;r<4;++r){
    int oy=threadIdx.y + r*8, ox=threadIdx.x;
    int gy=by+oy, gx=bx+ox;
    bool pos=false; u64 key=0;
    if (gy<Hh && gx<Ww){
      float v=Ss[oy+3][ox+3];
      if (v>0.0f){
        float m=0.0f;
        #pragma unroll
        for(int dy=0;dy<7;dy++)
          #pragma unroll
          for(int dx=0;dx<7;dx++)
            m=fmaxf(m,Ss[oy+dy][ox+dx]);
        if (v>=m-NMS_EPS){
          u32 idx=(u32)(gy*Ww+gx);
          key=((u64)__float_as_uint(v)<<32)|(u64)(0xFFFFFFFFu-idx);  // value desc, index asc
          pos=true;
        }
      }
    }
    u64 mask=__ballot(pos);
    if (mask){
      int lane=t&63;
      int leader=__ffsll((long long)mask)-1;
      int base=0;
      if (lane==leader) base=atomicAdd(&lcnt,__popcll(mask));
      base=__shfl(base,leader);
      if (pos){
        int rk=__popcll(mask & ((1ULL<<lane)-1ULL));
        keys[base+rk]=key;
      }
    }
  }
  __syncthreads();
  if (t==0 && lcnt>0) gbase=atomicAdd(&cnt[seg*64], lcnt);   // one atomic per block
  __syncthreads();
  int n=lcnt;
  for (int i=t;i<n;i+=256){
    int p=gbase+i;
    if (p<LISTCAP) lists[(size_t)seg*LISTCAP+p]=keys[i];
  }
}

// ---------------- radix-select top-K: histogram pass ----------------
__global__ void topk_hist(const u64* __restrict__ lists, const int* __restrict__ cnt,
                          const u64* __restrict__ prefix, const int* __restrict__ takeAll,
                          u32* __restrict__ ghist, int round){
  int seg=blockIdx.y;
  if(round>0 && takeAll[seg]) return;
  __shared__ u32 h[256];
  h[threadIdx.x]=0; __syncthreads();
  int n=imin(cnt[seg*64],LISTCAP);
  int shift=56-8*round;
  u64 maskHi=(round==0)?0ULL:(~0ULL<<(shift+8));
  u64 pfx=prefix[seg];
  for(int i=blockIdx.x*256+threadIdx.x;i<n;i+=gridDim.x*256){
    u64 k=lists[(size_t)seg*LISTCAP+i];
    if((k&maskHi)==pfx) atomicAdd(&h[(int)((k>>shift)&255ULL)],1u);
  }
  __syncthreads();
  if(h[threadIdx.x]) atomicAdd(&ghist[seg*256+threadIdx.x],h[threadIdx.x]);
}

// ---------------- radix-select: decide byte, advance state ----------------
__global__ void topk_decide(u32* __restrict__ ghist, const int* __restrict__ cnt,
                            int* __restrict__ krem, int* __restrict__ takeAll,
                            u64* __restrict__ prefix, u64* __restrict__ Tf, int round){
  int t=threadIdx.x;
  if(t<NSEG){
    int seg=t;
    if(round==0){
      krem[seg]=Kk;
      prefix[seg]=0ULL;
      takeAll[seg]=(imin(cnt[seg*64],LISTCAP)<=Kk)?1:0;
    }
    if(takeAll[seg]){
      if(round==7) Tf[seg]=1ULL;   // all keys >= 1 (value>0 => high bits nonzero)
    } else {
      int kr=krem[seg];
      const u32* h=&ghist[seg*256];
      int acc=0; int b=255;
      for(;b>0;--b){ int c2=(int)h[b]; if(acc+c2>=kr) break; acc+=c2; }
      int shift=56-8*round;
      prefix[seg]|=((u64)(u32)b)<<shift;
      krem[seg]=kr-acc;
      if(round==7) Tf[seg]=prefix[seg];
    }
  }
  __syncthreads();
  for(int i=t;i<NSEG*256;i+=blockDim.x) ghist[i]=0u;  // clear for next round
}

// ---------------- gather keys >= threshold (wave-aggregated atomic) ----------------
__global__ void topk_gather(const u64* __restrict__ lists, const int* __restrict__ cnt,
                            const u64* __restrict__ Tf, u64* __restrict__ selbuf, int* __restrict__ selcnt){
  int seg=blockIdx.y;
  int n=imin(cnt[seg*64],LISTCAP);
  u64 T=Tf[seg];
  for(int i0=blockIdx.x*256;i0<n;i0+=gridDim.x*256){
    int i=i0+threadIdx.x;
    bool sel=false; u64 k=0;
    if(i<n){ k=lists[(size_t)seg*LISTCAP+i]; sel=(k>=T); }
    u64 mask=__ballot(sel);
    if(mask){
      int lane=threadIdx.x&63;
      int leader=__ffsll((long long)mask)-1;
      int base=0;
      if(lane==leader) base=atomicAdd(&selcnt[seg*64],__popcll(mask));
      base=__shfl(base,leader);
      if(sel){
        int p=base+__popcll(mask & ((1ULL<<lane)-1ULL));
        if(p<Kk) selbuf[(size_t)seg*Kk+p]=k;
      }
    }
  }
}

// ---------------- sort 1024 keys desc, emit keypoint meta + k1/k2 ----------------
__global__ __launch_bounds__(1024) void finalize_kernel(const u64* __restrict__ selbuf, const int* __restrict__ selcnt,
                                int* __restrict__ kyi, int* __restrict__ kxi, float* __restrict__ kval,
                                float* __restrict__ outp){
  int seg=blockIdx.x, tid=threadIdx.x;
  __shared__ u64 a[1024];
  int n=selcnt[seg*64]; if(n>Kk)n=Kk;
  a[tid]=(tid<n)?selbuf[(size_t)seg*Kk+tid]:0ULL;
  __syncthreads();
  for(int k=2;k<=1024;k<<=1){
    for(int j=k>>1;j>0;j>>=1){
      int ixj=tid^j;
      if(ixj>tid){
        u64 x=a[tid], y=a[ixj];
        bool desc=((tid&k)==0);
        if(desc ? (x<y) : (x>y)){ a[tid]=y; a[ixj]=x; }
      }
      __syncthreads();
    }
  }
  u64 key=a[tid];
  bool val=(key!=0ULL);
  u32 idx=0xFFFFFFFFu-(u32)(key&0xFFFFFFFFULL);
  int y= val ? (int)(idx/Ww) : 0;
  int x= val ? (int)(idx%Ww) : 0;
  int mi=seg*Kk+tid;
  kyi[mi]=y; kxi[mi]=x; kval[mi]= val?1.0f:0.0f;
  int imi=seg>>1, bb=seg&1;
  float* ko=outp + (size_t)imi*(Bb*Kk*2) + ((size_t)bb*Kk+tid)*2;
  ko[0]= val ? (float)y : -1.0f;
  ko[1]= val ? (float)x : -1.0f;
}

// ---------------- Gaussian weights (1D, normalized) ----------------
__global__ void init_weights(float* wn){
  if(threadIdx.x==0 && blockIdx.x==0){
    double w[15]; double S=0.0;
    for(int i=0;i<15;i++){ double c=(double)i-7.0; w[i]=exp(-(c*c)/(2.0*2.5*2.5)); S+=w[i]; }
    for(int i=0;i<15;i++) wn[i]=(float)(w[i]/S);
  }
}

__device__ __forceinline__ float ldz(const float* __restrict__ img,int y,int x){
  return (y>=0&&y<Hh&&x>=0&&x<Ww)?img[(size_t)y*Ww+x]:0.0f;
}

// ---------------- per-keypoint orientation (15x15 Gaussian-weighted Sobel) ----------------
__global__ __launch_bounds__(64) void orient_kernel(const float* __restrict__ img1, const float* __restrict__ img2,
                              const int* __restrict__ kyi, const int* __restrict__ kxi,
                              const float* __restrict__ wn, float* __restrict__ kth){
  int seg=blockIdx.y, ki=blockIdx.x, lane=threadIdx.x;
  __shared__ float w15[15];
  if(lane<15) w15[lane]=wn[lane];
  __syncthreads();
  const float* img=(seg<2?img1:img2)+(size_t)(seg&1)*HWp;
  int mi=seg*Kk+ki;
  int yc=kyi[mi], xc=kxi[mi];
  float ax=0.0f, ay=0.0f;
  for(int tp=lane;tp<225;tp+=64){
    int du=tp/15-7, dv=tp-(tp/15)*15-7;
    int yy=yc+du, xx=xc+dv;
    if(yy<0||yy>=Hh||xx<0||xx>=Ww) continue;   // zero-pad of Sobel output
    float p00=ldz(img,yy-1,xx-1), p01=ldz(img,yy-1,xx), p02=ldz(img,yy-1,xx+1);
    float p10=ldz(img,yy,xx-1),                          p12=ldz(img,yy,xx+1);
    float p20=ldz(img,yy+1,xx-1), p21=ldz(img,yy+1,xx), p22=ldz(img,yy+1,xx+1);
    float sx=(-p00+p02-2.0f*p10+2.0f*p12-p20+p22)*0.125f;
    float sy=(-p00-2.0f*p01-p02+p20+2.0f*p21+p22)*0.125f;
    float wgt=w15[du+7]*w15[dv+7];
    ax=fmaf(wgt,sx,ax); ay=fmaf(wgt,sy,ay);
  }
  for(int o=32;o;o>>=1){ ax+=__shfl_down(ax,o); ay+=__shfl_down(ay,o); }
  if(lane==0) kth[mi]=atan2f(ay,ax);
}

// ---------------- BAD descriptor: LDS-staged 57x57 patch + box samples + normalize ----------------
__global__ __launch_bounds__(256) void bad_kernel(const float* __restrict__ img1, const float* __restrict__ img2,
                           const float* __restrict__ offs, const float* __restrict__ thrv,
                           const int* __restrict__ rad,
                           const int* __restrict__ kyi, const int* __restrict__ kxi,
                           const float* __restrict__ kval, const float* __restrict__ kth,
                           float* __restrict__ d1, float* __restrict__ d2,
                           float* __restrict__ sq1, float* __restrict__ sq2){
  __shared__ float patch[PS][PS+1];
  __shared__ float sm[4];
  __shared__ float nsh;
  int seg=blockIdx.y, ki=blockIdx.x, p=threadIdx.x;
  const float* img=(seg<2?img1:img2)+(size_t)(seg&1)*HWp;
  int mi=seg*Kk+ki;
  int yci=kyi[mi], xci=kxi[mi];
  // stage the 57x57 neighborhood (zero outside image; "skip" == "+0.0f")
  for (int i=p;i<PS*PS;i+=256){
    int ly=i/PS, lx=i-ly*PS;
    int gy=yci-PR+ly, gx=xci-PR+lx;
    patch[ly][lx]=(gy>=0&&gy<Hh&&gx>=0&&gx<Ww)?img[(size_t)gy*Ww+gx]:0.0f;
  }
  __syncthreads();
  float yc=(float)yci, xc=(float)xci;
  float th=kth[mi];
  float c=cosf(th), s=sinf(th);
  float ox1=offs[p*4+0], oy1=offs[p*4+1], ox2=offs[p*4+2], oy2=offs[p*4+3];
  int r=rad[p];
  float w=WR[r];
  float px1=xc+c*ox1-s*oy1, py1=yc+s*ox1+c*oy1;
  float px2=xc+c*ox2-s*oy2, py2=yc+s*ox2+c*oy2;
  // local boxsum from LDS (same tap order & arithmetic as global version)
  auto boxl=[&](float px,float py,int r_)->float{
    float rx=rintf(px), ry=rintf(py);
    int xi=(int)fminf(fmaxf(rx,0.0f),(float)(Ww-1));
    int yi=(int)fminf(fmaxf(ry,0.0f),(float)(Hh-1));
    int lx=xi-(xci-PR), ly=yi-(yci-PR);   // guaranteed in [5,51]
    float acc=0.0f;
    for(int dy=-r_;dy<=r_;dy++){
      const float* rowp=&patch[ly+dy][lx];
      for(int dx=-r_;dx<=r_;dx++) acc+=rowp[dx];
    }
    return acc;
  };
  float s1=boxl(px1,py1,r)*w;
  float s2=boxl(px2,py2,r)*w;
  float v=(s1-s2-thrv[p])*kval[mi];
  float t=v*v;
  for(int o=32;o;o>>=1) t+=__shfl_down(t,o);
  if((p&63)==0) sm[p>>6]=t;
  __syncthreads();
  if(p==0) nsh=sqrtf(sm[0]+sm[1]+sm[2]+sm[3]);
  __syncthreads();
  float dv=v/(nsh+1e-8f);
  float* dd=(seg<2?d1:d2);
  dd[((size_t)(seg&1)*Kk+ki)*Pp+p]=dv;
  float t2=dv*dv;
  for(int o=32;o;o>>=1) t2+=__shfl_down(t2,o);
  __syncthreads();
  if((p&63)==0) sm[p>>6]=t2;
  __syncthreads();
  if(p==0){ float* sq=(seg<2?sq1:sq2); sq[(size_t)(seg&1)*Kk+ki]=sm[0]+sm[1]+sm[2]+sm[3]; }
}

// ---------------- pairwise distance -> Z (padded stride, and transposed copy) ----------------
// 64x64 tile, 4x4 register blocking, transposed LDS (float4, conflict-free)
__global__ __launch_bounds__(256) void dist_kernel(const float* __restrict__ d1, const float* __restrict__ d2,
                            const float* __restrict__ sq1, const float* __restrict__ sq2,
                            float* __restrict__ Zm, float* __restrict__ Zt){
  int b=blockIdx.z;
  int i0=blockIdx.y*64, j0=blockIdx.x*64;
  int tid=threadIdx.x;
  int tx=tid&15, ty=tid>>4;
  __shared__ float Ast[64][68], Bst[64][68];   // [k][row], [k][col]
  const float* D1=d1+(size_t)b*Kk*Pp;
  const float* D2=d2+(size_t)b*Kk*Pp;
  float acc[4][4]={};
  for(int p0=0;p0<Pp;p0+=64){
    for(int i=tid;i<64*16;i+=256){
      int row=i>>4, c4=(i&15)<<2;
      float4 va=*reinterpret_cast<const float4*>(&D1[(size_t)(i0+row)*Pp+p0+c4]);
      float4 vb=*reinterpret_cast<const float4*>(&D2[(size_t)(j0+row)*Pp+p0+c4]);
      Ast[c4+0][row]=va.x; Ast[c4+1][row]=va.y; Ast[c4+2][row]=va.z; Ast[c4+3][row]=va.w;
      Bst[c4+0][row]=vb.x; Bst[c4+1][row]=vb.y; Bst[c4+2][row]=vb.z; Bst[c4+3][row]=vb.w;
    }
    __syncthreads();
    #pragma unroll 8
    for(int kk=0;kk<64;++kk){
      float4 av=*reinterpret_cast<const float4*>(&Ast[kk][ty*4]);
      float4 bv=*reinterpret_cast<const float4*>(&Bst[kk][tx*4]);
      acc[0][0]=fmaf(av.x,bv.x,acc[0][0]); acc[0][1]=fmaf(av.x,bv.y,acc[0][1]);
      acc[0][2]=fmaf(av.x,bv.z,acc[0][2]); acc[0][3]=fmaf(av.x,bv.w,acc[0][3]);
      acc[1][0]=fmaf(av.y,bv.x,acc[1][0]); acc[1][1]=fmaf(av.y,bv.y,acc[1][1]);
      acc[1][2]=fmaf(av.y,bv.z,acc[1][2]); acc[1][3]=fmaf(av.y,bv.w,acc[1][3]);
      acc[2][0]=fmaf(av.z,bv.x,acc[2][0]); acc[2][1]=fmaf(av.z,bv.y,acc[2][1]);
      acc[2][2]=fmaf(av.z,bv.z,acc[2][2]); acc[2][3]=fmaf(av.z,bv.w,acc[2][3]);
      acc[3][0]=fmaf(av.w,bv.x,acc[3][0]); acc[3][1]=fmaf(av.w,bv.y,acc[3][1]);
      acc[3][2]=fmaf(av.w,bv.z,acc[3][2]); acc[3][3]=fmaf(av.w,bv.w,acc[3][3]);
    }
    __syncthreads();
  }
  int gi=i0+ty*4, gj=j0+tx*4;
  float si[4], sj[4];
  #pragma unroll
  for(int i=0;i<4;i++){ si[i]=sq1[b*Kk+gi+i]; sj[i]=sq2[b*Kk+gj+i]; }
  #pragma unroll
  for(int i=0;i<4;i++){
    #pragma unroll
    for(int j=0;j<4;j++){
      float dd=si[i]+sj[j]-2.0f*acc[i][j];
      float dist=sqrtf(fmaxf(dd,0.0f)+1e-12f);
      Zm[(size_t)b*ZB+(size_t)(gi+i)*ZLD+(gj+j)]=-dist;
      Zt[(size_t)b*ZB+(size_t)(gj+j)*ZLD+(gi+i)]=-dist;
    }
  }
}

// border (=1.0) + pad columns (=-1e30 so exp -> 0 with o_pad=0)
__global__ void zborder_kernel(float* __restrict__ Zm, float* __restrict__ Zt){
  int i=blockIdx.x*256+threadIdx.x;
  if(i>=Bb*KP1) return;
  int b=i/KP1, j=i-(i/KP1)*KP1;
  size_t base=(size_t)b*ZB;
  Zm[base+(size_t)j*ZLD+Kk]=1.0f;
  Zm[base+(size_t)Kk*ZLD+j]=1.0f;
  Zt[base+(size_t)j*ZLD+Kk]=1.0f;
  Zt[base+(size_t)Kk*ZLD+j]=1.0f;
  for(int c=KP1;c<ZLD;c++){
    Zm[base+(size_t)j*ZLD+c]=-1.0e30f;
    Zt[base+(size_t)j*ZLD+c]=-1.0e30f;
  }
}

// ---------------- Sinkhorn half-iteration: res = log_mu - log sum exp(Z[i,:]+o[:]) ----------------
// One wave per row, float4 over padded rows; single pass (arguments bounded).
__global__ __launch_bounds__(256) void sink_lse(const float* __restrict__ Zm, const float* __restrict__ ov,
                                                float* __restrict__ res){
  int row=blockIdx.x*4+(threadIdx.x>>6);
  if(row>=Bb*KP1) return;
  int b=row/KP1, i=row-b*KP1;
  int lane=threadIdx.x&63;
  const float4* rp=reinterpret_cast<const float4*>(Zm+(size_t)b*ZB+(size_t)i*ZLD);
  const float4* o4=reinterpret_cast<const float4*>(ov+(size_t)b*ZLD);
  float s=0.0f;
  for(int j=lane;j<ZLD/4;j+=64){
    float4 z=rp[j], o=o4[j];
    s+=expf(z.x+o.x)+expf(z.y+o.y)+expf(z.z+o.z)+expf(z.w+o.w);
  }
  for(int off=32;off;off>>=1) s+=__shfl_down(s,off);
  if(lane==0){
    float lm=(i<Kk)?NORMV:(LOGKV+NORMV);
    res[(size_t)b*ZLD+i]=lm-logf(s);
  }
}

// ---------------- final probs = exp(Z+u+v-norm) ----------------
__global__ void probs_kernel(const float* __restrict__ Zm, const float* __restrict__ uu,
                             const float* __restrict__ vv, float* __restrict__ outp){
  size_t i=(size_t)blockIdx.x*256+threadIdx.x;
  const size_t tot=(size_t)Bb*KP1*KP1;
  if(i>=tot) return;
  size_t b=i/((size_t)KP1*KP1);
  size_t rem=i-b*(size_t)KP1*KP1;
  int rr=(int)(rem/KP1), cc=(int)(rem-(size_t)(rem/KP1)*KP1);
  outp[i]=expf(Zm[b*ZB+(size_t)rr*ZLD+cc]+uu[b*ZLD+rr]+vv[b*ZLD+cc]-NORMV);
}

extern "C" void kernel_launch(void* const* d_in, const int* in_sizes, int n_in,
                              void* d_out, int out_size, void* d_ws, size_t ws_size,
                              hipStream_t stream) {
  (void)in_sizes; (void)n_in; (void)out_size; (void)ws_size;
  const float* img1=(const float*)d_in[0];
  const float* img2=(const float*)d_in[1];
  const float* offs=(const float*)d_in[2];
  const float* thrv=(const float*)d_in[3];
  const int*   rad =(const int*)d_in[4];
  float* out=(float*)d_out;

  char* wp=(char*)d_ws;
  auto carve=[&](size_t bytes)->char*{ char* p=wp; wp += (bytes+255)&~(size_t)255; return p; };
  float* r0  =(float*)carve(PLn*4);            // L ping / Z (padded)
  float* r1  =(float*)carve(PLn*4);            // L pong / Zt (padded)
  float* resp=(float*)carve(PLn*4);
  u64*  lists=(u64*)carve((size_t)NSEG*LISTCAP*8);
  char* stateblk = carve(8192);
  int* cnt     =(int*)(stateblk);              // [seg*64], 256B stride per seg
  int* selcnt  =(int*)(stateblk+1024);         // [seg*64]
  int* krem    =(int*)(stateblk+2048);
  int* takeAll =(int*)(stateblk+2112);
  u64* prefix  =(u64*)(stateblk+2176);
  u64* Tf      =(u64*)(stateblk+2240);
  u32* ghist   =(u32*)(stateblk+2304);         // 4KB
  u64* selbuf  =(u64*)carve((size_t)NSEG*Kk*8);
  int* kyi     =(int*)carve((size_t)NSEG*Kk*4);
  int* kxi     =(int*)carve((size_t)NSEG*Kk*4);
  float* kval  =(float*)carve((size_t)NSEG*Kk*4);
  float* kth   =(float*)carve((size_t)NSEG*Kk*4);
  float* d1    =(float*)carve((size_t)Bb*Kk*Pp*4);
  float* d2    =(float*)carve((size_t)Bb*Kk*Pp*4);
  float* sq1   =(float*)carve((size_t)Bb*Kk*4);
  float* sq2   =(float*)carve((size_t)Bb*Kk*4);
  float* uvec  =(float*)carve((size_t)Bb*ZLD*4);
  float* vvec  =(float*)carve((size_t)Bb*ZLD*4);
  float* wn    =(float*)carve(64);

  hipMemsetAsync(stateblk, 0, 8192, stream);
  init_weights<<<1,32,0,stream>>>(wn);

  dim3 TG(Ww/32, Hh/32, Bb), TB(32,8);
  for(int im=0; im<2; ++im){
    const float* srcimg = (im==0)? img1 : img2;
    hipMemsetAsync(resp, 0, PLn*4, stream);
    hipMemcpyAsync(r0, srcimg, PLn*4, hipMemcpyDeviceToDevice, stream);
    float* cur=r0; float* oth=r1;
    for(int st=1; st<=9; ++st){
      fed_step<<<TG,TB,0,stream>>>(cur, oth);
      float* tp=cur; cur=oth; oth=tp;
      if(st%3==0) response_kernel<<<TG,TB,0,stream>>>(cur, resp);
    }
    detect_compact<<<TG,TB,0,stream>>>(resp, lists, cnt, im*2);
  }

  for(int rd=0; rd<8; ++rd){
    topk_hist<<<dim3(32,NSEG),dim3(256),0,stream>>>(lists, cnt, prefix, takeAll, ghist, rd);
    topk_decide<<<1,256,0,stream>>>(ghist, cnt, krem, takeAll, prefix, Tf, rd);
  }
  topk_gather<<<dim3(64,NSEG),dim3(256),0,stream>>>(lists, cnt, Tf, selbuf, selcnt);
  finalize_kernel<<<NSEG,1024,0,stream>>>(selbuf, selcnt, kyi, kxi, kval, out);
  orient_kernel<<<dim3(Kk,NSEG),dim3(64),0,stream>>>(img1, img2, kyi, kxi, wn, kth);
  bad_kernel<<<dim3(Kk,NSEG),dim3(256),0,stream>>>(img1, img2, offs, thrv, rad,
                                                   kyi, kxi, kval, kth, d1, d2, sq1, sq2);

  float* Zm=r0; float* Zt=r1;   // reuse image buffers (padded Z layout fits)
  dist_kernel<<<dim3(16,16,Bb),dim3(256),0,stream>>>(d1,d2,sq1,sq2,Zm,Zt);
  zborder_kernel<<<dim3((Bb*KP1+255)/256),dim3(256),0,stream>>>(Zm,Zt);
  hipMemsetAsync(uvec,0,(size_t)Bb*ZLD*4,stream);
  hipMemsetAsync(vvec,0,(size_t)Bb*ZLD*4,stream);
  for(int it=0; it<20; ++it){
    sink_lse<<<dim3((Bb*KP1+3)/4),dim3(256),0,stream>>>(Zm, vvec, uvec);
    sink_lse<<<dim3((Bb*KP1+3)/4),dim3(256),0,stream>>>(Zt, uvec, vvec);
  }
  size_t tot=(size_t)Bb*KP1*KP1;
  probs_kernel<<<dim3((u32)((tot+255)/256)),dim3(256),0,stream>>>(Zm, uvec, vvec, out + (size_t)2*Bb*Kk*2);
}

// Round 6
// 717.975 us; speedup vs baseline: 1.3779x; 1.1654x over previous
//
#include <hip/hip_runtime.h>
#include <math.h>

typedef unsigned long long u64;
typedef unsigned int u32;

#define Hh 960
#define Ww 1280
#define Bb 2
#define Kk 1024
#define Pp 256
#define KP1 1025
#define NSEG 4
#define LISTCAP 131072
#define PR 28
#define PS 57
#define ZLD 1040                         /* padded Z row stride (16B-aligned) */
static const size_t ZB = (size_t)KP1*ZLD;  // per-batch Z floats

static const size_t HWp = (size_t)Hh * Ww;   // one plane
static const size_t PLn = HWp * Bb;          // B planes

#define TAUf 0.2f
#define NMS_EPS 1e-7f
#define DET_T 0.001f
#define NORMV (-7.6246189861593985f)   /* -log(2*K) */
#define LOGKV (6.9314718055994531f)    /* log(K) */

__constant__ float WR[6] = {1.0f, 1.0f/9.0f, 1.0f/25.0f, 1.0f/49.0f, 1.0f/81.0f, 1.0f/121.0f};

__device__ __forceinline__ int imin(int a,int b){return a<b?a:b;}
__device__ __forceinline__ int imax(int a,int b){return a>b?a:b;}

// ---------------- FED diffusion step (fused: Sobel->g->flux) ----------------
__global__ __launch_bounds__(256) void fed_step(const float* __restrict__ src, float* __restrict__ dst){
  __shared__ float Lt[36][37];
  __shared__ float Gt[34][35];
  const int bx = blockIdx.x*32, by = blockIdx.y*32, b = blockIdx.z;
  const float* S = src + (size_t)b*HWp;
  float* D = dst + (size_t)b*HWp;
  const int t = threadIdx.y*32 + threadIdx.x;
  for (int i=t;i<36*36;i+=256){
    int ly=i/36, lx=i-ly*36;
    int gy=by+ly-2, gx=bx+lx-2;
    Lt[ly][lx] = (gy>=0 && gy<Hh && gx>=0 && gx<Ww) ? S[(size_t)gy*Ww+gx] : 0.0f;  // zero-pad for Sobel
  }
  __syncthreads();
  const float k2 = (float)(0.05*0.05);
  for (int i=t;i<34*34;i+=256){
    int ly=i/34, lx=i-ly*34;
    int Ly=ly+1, Lx=lx+1;
    float sx = (-Lt[Ly-1][Lx-1]+Lt[Ly-1][Lx+1]
                -2.0f*Lt[Ly][Lx-1]+2.0f*Lt[Ly][Lx+1]
                -Lt[Ly+1][Lx-1]+Lt[Ly+1][Lx+1])*0.125f;
    float sy = (-Lt[Ly-1][Lx-1]-2.0f*Lt[Ly-1][Lx]-Lt[Ly-1][Lx+1]
                +Lt[Ly+1][Lx-1]+2.0f*Lt[Ly+1][Lx]+Lt[Ly+1][Lx+1])*0.125f;
    Gt[ly][lx] = 1.0f/(1.0f + (sx*sx+sy*sy)/k2);
  }
  __syncthreads();
  for (int r=0;r<4;++r){
    int oy=threadIdx.y + r*8, ox=threadIdx.x;
    int gy=by+oy, gx=bx+ox;
    if (gy>=Hh || gx>=Ww) continue;
    // edge-clamped neighbor coordinates (matches np.pad 'edge')
    int gyn=imax(gy-1,0), gys=imin(gy+1,Hh-1), gxw=imax(gx-1,0), gxe=imin(gx+1,Ww-1);
    float Lc=Lt[oy+2][ox+2];
    float Ln=Lt[gyn-by+2][ox+2];
    float Ls=Lt[gys-by+2][ox+2];
    float Lw=Lt[oy+2][gxw-bx+2];
    float Le=Lt[oy+2][gxe-bx+2];
    float gc=Gt[oy+1][ox+1];
    float gn=Gt[gyn-by+1][ox+1];
    float gs=Gt[gys-by+1][ox+1];
    float gw=Gt[oy+1][gxw-bx+1];
    float ge=Gt[oy+1][gxe-bx+1];
    float flux = 0.5f*((gc+gn)*(Ln-Lc) + (gc+gs)*(Ls-Lc) + (gc+gw)*(Lw-Lc) + (gc+ge)*(Le-Lc));
    D[(size_t)gy*Ww+gx] = Lc + TAUf*flux;
  }
}

// ---------------- Hessian response (Lxx*Lyy - Lxy^2), resp = max(resp, det) ----------------
__global__ __launch_bounds__(256) void response_kernel(const float* __restrict__ src, float* __restrict__ resp){
  __shared__ float Lt[36][37];
  __shared__ float Sx[34][35];
  const int bx = blockIdx.x*32, by = blockIdx.y*32, b = blockIdx.z;
  const float* S = src + (size_t)b*HWp;
  float* R = resp + (size_t)b*HWp;
  const int t = threadIdx.y*32 + threadIdx.x;
  for (int i=t;i<36*36;i+=256){
    int ly=i/36, lx=i-ly*36;
    int gy=by+ly-2, gx=bx+lx-2;
    Lt[ly][lx] = (gy>=0 && gy<Hh && gx>=0 && gx<Ww) ? S[(size_t)gy*Ww+gx] : 0.0f;
  }
  __syncthreads();
  for (int i=t;i<34*34;i+=256){
    int ly=i/34, lx=i-ly*34;
    int gy=by+ly-1, gx=bx+lx-1;
    float v=0.0f;
    if (gy>=0 && gy<Hh && gx>=0 && gx<Ww){   // Sx is zero outside image (zero-pad of first conv's output)
      int Ly=ly+1, Lx=lx+1;
      v = (-Lt[Ly-1][Lx-1]+Lt[Ly-1][Lx+1]
           -2.0f*Lt[Ly][Lx-1]+2.0f*Lt[Ly][Lx+1]
           -Lt[Ly+1][Lx-1]+Lt[Ly+1][Lx+1])*0.125f;
    }
    Sx[ly][lx]=v;
  }
  __syncthreads();
  for (int r=0;r<4;++r){
    int oy=threadIdx.y + r*8, ox=threadIdx.x;
    int gy=by+oy, gx=bx+ox;
    if (gy>=Hh || gx>=Ww) continue;
    int Ly=oy+2, Lx=ox+2;
    float Lxx = Lt[Ly][Lx-1]-2.0f*Lt[Ly][Lx]+Lt[Ly][Lx+1];
    float Lyy = Lt[Ly-1][Lx]-2.0f*Lt[Ly][Lx]+Lt[Ly+1][Lx];
    int Sy=oy+1, Sxi=ox+1;
    float Lxy = (-Sx[Sy-1][Sxi-1]-2.0f*Sx[Sy-1][Sxi]-Sx[Sy-1][Sxi+1]
                 +Sx[Sy+1][Sxi-1]+2.0f*Sx[Sy+1][Sxi]+Sx[Sy+1][Sxi+1])*0.125f;
    float det = Lxx*Lyy - Lxy*Lxy;
    size_t id=(size_t)gy*Ww+gx;
    R[id] = fmaxf(R[id], det);
  }
}

// ---------------- fused: threshold + 5x5 NMS + 7x7 NMS + block compaction ----------------
__global__ __launch_bounds__(256) void detect_compact(const float* __restrict__ resp,
                                                      u64* __restrict__ lists,
                                                      int* __restrict__ cnt, int segbase){
  const int TS=42;                 // 32 + 2*5 halo (3 for 7x7 + 2 for the 5x5 mask in the halo)
  __shared__ float Tt[TS][TS+1];   // thresholded response
  __shared__ float Ss[38][39];     // 5x5-NMS-masked, halo 3
  __shared__ u64 keys[1024];
  __shared__ int lcnt, gbase;
  const int bx = blockIdx.x*32, by = blockIdx.y*32, b = blockIdx.z;
  const float* S = resp + (size_t)b*HWp;
  const int t = threadIdx.y*32 + threadIdx.x;
  if (t==0) lcnt=0;
  for (int i=t;i<TS*TS;i+=256){
    int ly=i/TS, lx=i-ly*TS;
    int gy=by+ly-5, gx=bx+lx-5;
    float v = (gy>=0 && gy<Hh && gx>=0 && gx<Ww) ? S[(size_t)gy*Ww+gx] : 0.0f;
    Tt[ly][lx] = (v>DET_T) ? v : 0.0f;
  }
  __syncthreads();
  for (int i=t;i<38*38;i+=256){
    int ly=i/38, lx=i-ly*38;
    int ty=ly+2, tx=lx+2;
    float m=0.0f;
    #pragma unroll
    for(int dy=-2;dy<=2;dy++)
      #pragma unroll
      for(int dx=-2;dx<=2;dx++)
        m=fmaxf(m,Tt[ty+dy][tx+dx]);
    float c=Tt[ty][tx];
    Ss[ly][lx]=(c>=m-NMS_EPS)?c:0.0f;
  }
  __syncthreads();
  const int seg=segbase+b;
  for (int r=0;r<4;++r){
    int oy=threadIdx.y + r*8, ox=threadIdx.x;
    int gy=by+oy, gx=bx+ox;
    bool pos=false; u64 key=0;
    if (gy<Hh && gx<Ww){
      float v=Ss[oy+3][ox+3];
      if (v>0.0f){
        float m=0.0f;
        #pragma unroll
        for(int dy=0;dy<7;dy++)
          #pragma unroll
          for(int dx=0;dx<7;dx++)
            m=fmaxf(m,Ss[oy+dy][ox+dx]);
        if (v>=m-NMS_EPS){
          u32 idx=(u32)(gy*Ww+gx);
          key=((u64)__float_as_uint(v)<<32)|(u64)(0xFFFFFFFFu-idx);  // value desc, index asc
          pos=true;
        }
      }
    }
    u64 mask=__ballot(pos);
    if (mask){
      int lane=t&63;
      int leader=__ffsll((long long)mask)-1;
      int base=0;
      if (lane==leader) base=atomicAdd(&lcnt,__popcll(mask));
      base=__shfl(base,leader);
      if (pos){
        int rk=__popcll(mask & ((1ULL<<lane)-1ULL));
        keys[base+rk]=key;
      }
    }
  }
  __syncthreads();
  if (t==0 && lcnt>0) gbase=atomicAdd(&cnt[seg*64], lcnt);   // one atomic per block
  __syncthreads();
  int n=lcnt;
  for (int i=t;i<n;i+=256){
    int p=gbase+i;
    if (p<LISTCAP) lists[(size_t)seg*LISTCAP+p]=keys[i];
  }
}

// ---------------- radix-select top-K: histogram pass ----------------
__global__ void topk_hist(const u64* __restrict__ lists, const int* __restrict__ cnt,
                          const u64* __restrict__ prefix, const int* __restrict__ takeAll,
                          u32* __restrict__ ghist, int round){
  int seg=blockIdx.y;
  if(round>0 && takeAll[seg]) return;
  __shared__ u32 h[256];
  h[threadIdx.x]=0; __syncthreads();
  int n=imin(cnt[seg*64],LISTCAP);
  int shift=56-8*round;
  u64 maskHi=(round==0)?0ULL:(~0ULL<<(shift+8));
  u64 pfx=prefix[seg];
  for(int i=blockIdx.x*256+threadIdx.x;i<n;i+=gridDim.x*256){
    u64 k=lists[(size_t)seg*LISTCAP+i];
    if((k&maskHi)==pfx) atomicAdd(&h[(int)((k>>shift)&255ULL)],1u);
  }
  __syncthreads();
  if(h[threadIdx.x]) atomicAdd(&ghist[seg*256+threadIdx.x],h[threadIdx.x]);
}

// ---------------- radix-select: decide byte, advance state ----------------
__global__ void topk_decide(u32* __restrict__ ghist, const int* __restrict__ cnt,
                            int* __restrict__ krem, int* __restrict__ takeAll,
                            u64* __restrict__ prefix, u64* __restrict__ Tf, int round){
  int t=threadIdx.x;
  if(t<NSEG){
    int seg=t;
    if(round==0){
      krem[seg]=Kk;
      prefix[seg]=0ULL;
      takeAll[seg]=(imin(cnt[seg*64],LISTCAP)<=Kk)?1:0;
    }
    if(takeAll[seg]){
      if(round==7) Tf[seg]=1ULL;   // all keys >= 1 (value>0 => high bits nonzero)
    } else {
      int kr=krem[seg];
      const u32* h=&ghist[seg*256];
      int acc=0; int b=255;
      for(;b>0;--b){ int c2=(int)h[b]; if(acc+c2>=kr) break; acc+=c2; }
      int shift=56-8*round;
      prefix[seg]|=((u64)(u32)b)<<shift;
      krem[seg]=kr-acc;
      if(round==7) Tf[seg]=prefix[seg];
    }
  }
  __syncthreads();
  for(int i=t;i<NSEG*256;i+=blockDim.x) ghist[i]=0u;  // clear for next round
}

// ---------------- gather keys >= threshold (wave-aggregated atomic) ----------------
__global__ void topk_gather(const u64* __restrict__ lists, const int* __restrict__ cnt,
                            const u64* __restrict__ Tf, u64* __restrict__ selbuf, int* __restrict__ selcnt){
  int seg=blockIdx.y;
  int n=imin(cnt[seg*64],LISTCAP);
  u64 T=Tf[seg];
  for(int i0=blockIdx.x*256;i0<n;i0+=gridDim.x*256){
    int i=i0+threadIdx.x;
    bool sel=false; u64 k=0;
    if(i<n){ k=lists[(size_t)seg*LISTCAP+i]; sel=(k>=T); }
    u64 mask=__ballot(sel);
    if(mask){
      int lane=threadIdx.x&63;
      int leader=__ffsll((long long)mask)-1;
      int base=0;
      if(lane==leader) base=atomicAdd(&selcnt[seg*64],__popcll(mask));
      base=__shfl(base,leader);
      if(sel){
        int p=base+__popcll(mask & ((1ULL<<lane)-1ULL));
        if(p<Kk) selbuf[(size_t)seg*Kk+p]=k;
      }
    }
  }
}

// ---------------- sort 1024 keys desc, emit keypoint meta + k1/k2 ----------------
__global__ __launch_bounds__(1024) void finalize_kernel(const u64* __restrict__ selbuf, const int* __restrict__ selcnt,
                                int* __restrict__ kyi, int* __restrict__ kxi, float* __restrict__ kval,
                                float* __restrict__ outp){
  int seg=blockIdx.x, tid=threadIdx.x;
  __shared__ u64 a[1024];
  int n=selcnt[seg*64]; if(n>Kk)n=Kk;
  a[tid]=(tid<n)?selbuf[(size_t)seg*Kk+tid]:0ULL;
  __syncthreads();
  for(int k=2;k<=1024;k<<=1){
    for(int j=k>>1;j>0;j>>=1){
      int ixj=tid^j;
      if(ixj>tid){
        u64 x=a[tid], y=a[ixj];
        bool desc=((tid&k)==0);
        if(desc ? (x<y) : (x>y)){ a[tid]=y; a[ixj]=x; }
      }
      __syncthreads();
    }
  }
  u64 key=a[tid];
  bool val=(key!=0ULL);
  u32 idx=0xFFFFFFFFu-(u32)(key&0xFFFFFFFFULL);
  int y= val ? (int)(idx/Ww) : 0;
  int x= val ? (int)(idx%Ww) : 0;
  int mi=seg*Kk+tid;
  kyi[mi]=y; kxi[mi]=x; kval[mi]= val?1.0f:0.0f;
  int imi=seg>>1, bb=seg&1;
  float* ko=outp + (size_t)imi*(Bb*Kk*2) + ((size_t)bb*Kk+tid)*2;
  ko[0]= val ? (float)y : -1.0f;
  ko[1]= val ? (float)x : -1.0f;
}

// ---------------- Gaussian weights (1D, normalized) ----------------
__global__ void init_weights(float* wn){
  if(threadIdx.x==0 && blockIdx.x==0){
    double w[15]; double S=0.0;
    for(int i=0;i<15;i++){ double c=(double)i-7.0; w[i]=exp(-(c*c)/(2.0*2.5*2.5)); S+=w[i]; }
    for(int i=0;i<15;i++) wn[i]=(float)(w[i]/S);
  }
}

__device__ __forceinline__ float ldz(const float* __restrict__ img,int y,int x){
  return (y>=0&&y<Hh&&x>=0&&x<Ww)?img[(size_t)y*Ww+x]:0.0f;
}

// ---------------- per-keypoint orientation (15x15 Gaussian-weighted Sobel) ----------------
__global__ __launch_bounds__(64) void orient_kernel(const float* __restrict__ img1, const float* __restrict__ img2,
                              const int* __restrict__ kyi, const int* __restrict__ kxi,
                              const float* __restrict__ wn, float* __restrict__ kth){
  int seg=blockIdx.y, ki=blockIdx.x, lane=threadIdx.x;
  __shared__ float w15[15];
  if(lane<15) w15[lane]=wn[lane];
  __syncthreads();
  const float* img=(seg<2?img1:img2)+(size_t)(seg&1)*HWp;
  int mi=seg*Kk+ki;
  int yc=kyi[mi], xc=kxi[mi];
  float ax=0.0f, ay=0.0f;
  for(int tp=lane;tp<225;tp+=64){
    int du=tp/15-7, dv=tp-(tp/15)*15-7;
    int yy=yc+du, xx=xc+dv;
    if(yy<0||yy>=Hh||xx<0||xx>=Ww) continue;   // zero-pad of Sobel output
    float p00=ldz(img,yy-1,xx-1), p01=ldz(img,yy-1,xx), p02=ldz(img,yy-1,xx+1);
    float p10=ldz(img,yy,xx-1),                          p12=ldz(img,yy,xx+1);
    float p20=ldz(img,yy+1,xx-1), p21=ldz(img,yy+1,xx), p22=ldz(img,yy+1,xx+1);
    float sx=(-p00+p02-2.0f*p10+2.0f*p12-p20+p22)*0.125f;
    float sy=(-p00-2.0f*p01-p02+p20+2.0f*p21+p22)*0.125f;
    float wgt=w15[du+7]*w15[dv+7];
    ax=fmaf(wgt,sx,ax); ay=fmaf(wgt,sy,ay);
  }
  for(int o=32;o;o>>=1){ ax+=__shfl_down(ax,o); ay+=__shfl_down(ay,o); }
  if(lane==0) kth[mi]=atan2f(ay,ax);
}

// ---------------- BAD descriptor: LDS summed-area table + 4-corner box sums ----------------
__global__ __launch_bounds__(256) void bad_kernel(const float* __restrict__ img1, const float* __restrict__ img2,
                           const float* __restrict__ offs, const float* __restrict__ thrv,
                           const int* __restrict__ rad,
                           const int* __restrict__ kyi, const int* __restrict__ kxi,
                           const float* __restrict__ kval, const float* __restrict__ kth,
                           float* __restrict__ d1, float* __restrict__ d2,
                           float* __restrict__ sq1, float* __restrict__ sq2){
  __shared__ float sat[PS+1][PS+2];     // 58 x 59; sat[y][x] = inclusive prefix of patch
  __shared__ float sm[4];
  __shared__ float nsh;
  int seg=blockIdx.y, ki=blockIdx.x, p=threadIdx.x;
  const float* img=(seg<2?img1:img2)+(size_t)(seg&1)*HWp;
  int mi=seg*Kk+ki;
  int yci=kyi[mi], xci=kxi[mi];
  // zero border row/col, stage 57x57 patch (zero outside image; "skip" == "+0.0f")
  for (int i=p;i<PS+1;i+=256){ sat[0][i]=0.0f; sat[i][0]=0.0f; }
  if (p==0) sat[0][PS]=0.0f;
  for (int i=p;i<PS*PS;i+=256){
    int ly=i/PS, lx=i-ly*PS;
    int gy=yci-PR+ly, gx=xci-PR+lx;
    sat[ly+1][lx+1]=(gy>=0&&gy<Hh&&gx>=0&&gx<Ww)?img[(size_t)gy*Ww+gx]:0.0f;
  }
  __syncthreads();
  // row prefix sums (57 lanes, stride-59 rows: conflict-free)
  if (p<PS){
    float run=0.0f;
    for(int x=1;x<=PS;x++){ run+=sat[p+1][x]; sat[p+1][x]=run; }
  }
  __syncthreads();
  // column prefix sums (57 lanes, consecutive addresses: conflict-free)
  if (p<PS){
    float run=0.0f;
    for(int y=1;y<=PS;y++){ run+=sat[y][p+1]; sat[y][p+1]=run; }
  }
  __syncthreads();
  float yc=(float)yci, xc=(float)xci;
  float th=kth[mi];
  float c=cosf(th), s=sinf(th);
  float ox1=offs[p*4+0], oy1=offs[p*4+1], ox2=offs[p*4+2], oy2=offs[p*4+3];
  int r=rad[p];
  float w=WR[r];
  float px1=xc+c*ox1-s*oy1, py1=yc+s*ox1+c*oy1;
  float px2=xc+c*ox2-s*oy2, py2=yc+s*ox2+c*oy2;
  // box sum via 4 SAT corners
  auto boxl=[&](float px,float py,int r_)->float{
    float rx=rintf(px), ry=rintf(py);
    int xi=(int)fminf(fmaxf(rx,0.0f),(float)(Ww-1));
    int yi=(int)fminf(fmaxf(ry,0.0f),(float)(Hh-1));
    int lx=xi-(xci-PR), ly=yi-(yci-PR);   // guaranteed in [5,51]
    int y2=ly+r_+1, y1=ly-r_, x2=lx+r_+1, x1=lx-r_;
    return sat[y2][x2]-sat[y1][x2]-sat[y2][x1]+sat[y1][x1];
  };
  float s1=boxl(px1,py1,r)*w;
  float s2=boxl(px2,py2,r)*w;
  float v=(s1-s2-thrv[p])*kval[mi];
  float t=v*v;
  for(int o=32;o;o>>=1) t+=__shfl_down(t,o);
  if((p&63)==0) sm[p>>6]=t;
  __syncthreads();
  if(p==0) nsh=sqrtf(sm[0]+sm[1]+sm[2]+sm[3]);
  __syncthreads();
  float dv=v/(nsh+1e-8f);
  float* dd=(seg<2?d1:d2);
  dd[((size_t)(seg&1)*Kk+ki)*Pp+p]=dv;
  float t2=dv*dv;
  for(int o=32;o;o>>=1) t2+=__shfl_down(t2,o);
  __syncthreads();
  if((p&63)==0) sm[p>>6]=t2;
  __syncthreads();
  if(p==0){ float* sq=(seg<2?sq1:sq2); sq[(size_t)(seg&1)*Kk+ki]=sm[0]+sm[1]+sm[2]+sm[3]; }
}

// ---------------- pairwise distance -> Z (padded stride, and transposed copy) ----------------
// 64x64 tile, 4x4 register blocking, transposed LDS (float4, conflict-free)
__global__ __launch_bounds__(256) void dist_kernel(const float* __restrict__ d1, const float* __restrict__ d2,
                            const float* __restrict__ sq1, const float* __restrict__ sq2,
                            float* __restrict__ Zm, float* __restrict__ Zt){
  int b=blockIdx.z;
  int i0=blockIdx.y*64, j0=blockIdx.x*64;
  int tid=threadIdx.x;
  int tx=tid&15, ty=tid>>4;
  __shared__ float Ast[64][68], Bst[64][68];   // [k][row], [k][col]
  const float* D1=d1+(size_t)b*Kk*Pp;
  const float* D2=d2+(size_t)b*Kk*Pp;
  float acc[4][4]={};
  for(int p0=0;p0<Pp;p0+=64){
    for(int i=tid;i<64*16;i+=256){
      int row=i>>4, c4=(i&15)<<2;
      float4 va=*reinterpret_cast<const float4*>(&D1[(size_t)(i0+row)*Pp+p0+c4]);
      float4 vb=*reinterpret_cast<const float4*>(&D2[(size_t)(j0+row)*Pp+p0+c4]);
      Ast[c4+0][row]=va.x; Ast[c4+1][row]=va.y; Ast[c4+2][row]=va.z; Ast[c4+3][row]=va.w;
      Bst[c4+0][row]=vb.x; Bst[c4+1][row]=vb.y; Bst[c4+2][row]=vb.z; Bst[c4+3][row]=vb.w;
    }
    __syncthreads();
    #pragma unroll 8
    for(int kk=0;kk<64;++kk){
      float4 av=*reinterpret_cast<const float4*>(&Ast[kk][ty*4]);
      float4 bv=*reinterpret_cast<const float4*>(&Bst[kk][tx*4]);
      acc[0][0]=fmaf(av.x,bv.x,acc[0][0]); acc[0][1]=fmaf(av.x,bv.y,acc[0][1]);
      acc[0][2]=fmaf(av.x,bv.z,acc[0][2]); acc[0][3]=fmaf(av.x,bv.w,acc[0][3]);
      acc[1][0]=fmaf(av.y,bv.x,acc[1][0]); acc[1][1]=fmaf(av.y,bv.y,acc[1][1]);
      acc[1][2]=fmaf(av.y,bv.z,acc[1][2]); acc[1][3]=fmaf(av.y,bv.w,acc[1][3]);
      acc[2][0]=fmaf(av.z,bv.x,acc[2][0]); acc[2][1]=fmaf(av.z,bv.y,acc[2][1]);
      acc[2][2]=fmaf(av.z,bv.z,acc[2][2]); acc[2][3]=fmaf(av.z,bv.w,acc[2][3]);
      acc[3][0]=fmaf(av.w,bv.x,acc[3][0]); acc[3][1]=fmaf(av.w,bv.y,acc[3][1]);
      acc[3][2]=fmaf(av.w,bv.z,acc[3][2]); acc[3][3]=fmaf(av.w,bv.w,acc[3][3]);
    }
    __syncthreads();
  }
  int gi=i0+ty*4, gj=j0+tx*4;
  float si[4], sj[4];
  #pragma unroll
  for(int i=0;i<4;i++){ si[i]=sq1[b*Kk+gi+i]; sj[i]=sq2[b*Kk+gj+i]; }
  #pragma unroll
  for(int i=0;i<4;i++){
    #pragma unroll
    for(int j=0;j<4;j++){
      float dd=si[i]+sj[j]-2.0f*acc[i][j];
      float dist=sqrtf(fmaxf(dd,0.0f)+1e-12f);
      Zm[(size_t)b*ZB+(size_t)(gi+i)*ZLD+(gj+j)]=-dist;
      Zt[(size_t)b*ZB+(size_t)(gj+j)*ZLD+(gi+i)]=-dist;
    }
  }
}

// border (=1.0) + pad columns (=-1e30 so exp -> 0 with o_pad=0)
__global__ void zborder_kernel(float* __restrict__ Zm, float* __restrict__ Zt){
  int i=blockIdx.x*256+threadIdx.x;
  if(i>=Bb*KP1) return;
  int b=i/KP1, j=i-(i/KP1)*KP1;
  size_t base=(size_t)b*ZB;
  Zm[base+(size_t)j*ZLD+Kk]=1.0f;
  Zm[base+(size_t)Kk*ZLD+j]=1.0f;
  Zt[base+(size_t)j*ZLD+Kk]=1.0f;
  Zt[base+(size_t)Kk*ZLD+j]=1.0f;
  for(int c=KP1;c<ZLD;c++){
    Zm[base+(size_t)j*ZLD+c]=-1.0e30f;
    Zt[base+(size_t)j*ZLD+c]=-1.0e30f;
  }
}

// ---------------- Sinkhorn half-iteration: res = log_mu - log sum exp(Z[i,:]+o[:]) ----------------
// One wave per row, float4 over padded rows; single pass (arguments bounded).
__global__ __launch_bounds__(256) void sink_lse(const float* __restrict__ Zm, const float* __restrict__ ov,
                                                float* __restrict__ res){
  int row=blockIdx.x*4+(threadIdx.x>>6);
  if(row>=Bb*KP1) return;
  int b=row/KP1, i=row-b*KP1;
  int lane=threadIdx.x&63;
  const float4* rp=reinterpret_cast<const float4*>(Zm+(size_t)b*ZB+(size_t)i*ZLD);
  const float4* o4=reinterpret_cast<const float4*>(ov+(size_t)b*ZLD);
  float s=0.0f;
  for(int j=lane;j<ZLD/4;j+=64){
    float4 z=rp[j], o=o4[j];
    s+=expf(z.x+o.x)+expf(z.y+o.y)+expf(z.z+o.z)+expf(z.w+o.w);
  }
  for(int off=32;off;off>>=1) s+=__shfl_down(s,off);
  if(lane==0){
    float lm=(i<Kk)?NORMV:(LOGKV+NORMV);
    res[(size_t)b*ZLD+i]=lm-logf(s);
  }
}

// ---------------- final probs = exp(Z+u+v-norm) ----------------
__global__ void probs_kernel(const float* __restrict__ Zm, const float* __restrict__ uu,
                             const float* __restrict__ vv, float* __restrict__ outp){
  size_t i=(size_t)blockIdx.x*256+threadIdx.x;
  const size_t tot=(size_t)Bb*KP1*KP1;
  if(i>=tot) return;
  size_t b=i/((size_t)KP1*KP1);
  size_t rem=i-b*(size_t)KP1*KP1;
  int rr=(int)(rem/KP1), cc=(int)(rem-(size_t)(rem/KP1)*KP1);
  outp[i]=expf(Zm[b*ZB+(size_t)rr*ZLD+cc]+uu[b*ZLD+rr]+vv[b*ZLD+cc]-NORMV);
}

extern "C" void kernel_launch(void* const* d_in, const int* in_sizes, int n_in,
                              void* d_out, int out_size, void* d_ws, size_t ws_size,
                              hipStream_t stream) {
  (void)in_sizes; (void)n_in; (void)out_size;
  const float* img1=(const float*)d_in[0];
  const float* img2=(const float*)d_in[1];
  const float* offs=(const float*)d_in[2];
  const float* thrv=(const float*)d_in[3];
  const int*   rad =(const int*)d_in[4];
  float* out=(float*)d_out;

  // batched (4-plane) diffusion if workspace allows, else 2-plane sequential
  const bool batched = ws_size >= ((size_t)72<<20);
  const int NP = batched ? 4 : 2;               // planes per stencil buffer
  const size_t PB = HWp*(size_t)NP*4;           // stencil buffer bytes

  char* wp=(char*)d_ws;
  auto carve=[&](size_t bytes)->char*{ char* p=wp; wp += (bytes+255)&~(size_t)255; return p; };
  float* r0  =(float*)carve(PB);               // L ping / Zm (padded Z fits: 8.53MB <= PB)
  float* r1  =(float*)carve(PB);               // L pong / Zt
  float* resp=(float*)carve(PB);
  u64*  lists=(u64*)carve((size_t)NSEG*LISTCAP*8);
  char* stateblk = carve(8192);
  int* cnt     =(int*)(stateblk);              // [seg*64], 256B stride per seg
  int* selcnt  =(int*)(stateblk+1024);         // [seg*64]
  int* krem    =(int*)(stateblk+2048);
  int* takeAll =(int*)(stateblk+2112);
  u64* prefix  =(u64*)(stateblk+2176);
  u64* Tf      =(u64*)(stateblk+2240);
  u32* ghist   =(u32*)(stateblk+2304);         // 4KB
  u64* selbuf  =(u64*)carve((size_t)NSEG*Kk*8);
  int* kyi     =(int*)carve((size_t)NSEG*Kk*4);
  int* kxi     =(int*)carve((size_t)NSEG*Kk*4);
  float* kval  =(float*)carve((size_t)NSEG*Kk*4);
  float* kth   =(float*)carve((size_t)NSEG*Kk*4);
  float* d1    =(float*)carve((size_t)Bb*Kk*Pp*4);
  float* d2    =(float*)carve((size_t)Bb*Kk*Pp*4);
  float* sq1   =(float*)carve((size_t)Bb*Kk*4);
  float* sq2   =(float*)carve((size_t)Bb*Kk*4);
  float* uvec  =(float*)carve((size_t)Bb*ZLD*4);
  float* vvec  =(float*)carve((size_t)Bb*ZLD*4);
  float* wn    =(float*)carve(64);

  hipMemsetAsync(stateblk, 0, 8192, stream);
  init_weights<<<1,32,0,stream>>>(wn);

  dim3 TB(32,8);
  if (batched){
    dim3 TG(Ww/32, Hh/32, 4);
    hipMemsetAsync(resp, 0, PB, stream);
    hipMemcpyAsync(r0,           img1, PLn*4, hipMemcpyDeviceToDevice, stream);
    hipMemcpyAsync(r0+2*HWp,     img2, PLn*4, hipMemcpyDeviceToDevice, stream);
    float* cur=r0; float* oth=r1;
    for(int st=1; st<=9; ++st){
      fed_step<<<TG,TB,0,stream>>>(cur, oth);
      float* tp=cur; cur=oth; oth=tp;
      if(st%3==0) response_kernel<<<TG,TB,0,stream>>>(cur, resp);
    }
    detect_compact<<<TG,TB,0,stream>>>(resp, lists, cnt, 0);
  } else {
    dim3 TG(Ww/32, Hh/32, Bb);
    for(int im=0; im<2; ++im){
      const float* srcimg = (im==0)? img1 : img2;
      hipMemsetAsync(resp, 0, PLn*4, stream);
      hipMemcpyAsync(r0, srcimg, PLn*4, hipMemcpyDeviceToDevice, stream);
      float* cur=r0; float* oth=r1;
      for(int st=1; st<=9; ++st){
        fed_step<<<TG,TB,0,stream>>>(cur, oth);
        float* tp=cur; cur=oth; oth=tp;
        if(st%3==0) response_kernel<<<TG,TB,0,stream>>>(cur, resp);
      }
      detect_compact<<<TG,TB,0,stream>>>(resp, lists, cnt, im*2);
    }
  }

  for(int rd=0; rd<8; ++rd){
    topk_hist<<<dim3(32,NSEG),dim3(256),0,stream>>>(lists, cnt, prefix, takeAll, ghist, rd);
    topk_decide<<<1,256,0,stream>>>(ghist, cnt, krem, takeAll, prefix, Tf, rd);
  }
  topk_gather<<<dim3(64,NSEG),dim3(256),0,stream>>>(lists, cnt, Tf, selbuf, selcnt);
  finalize_kernel<<<NSEG,1024,0,stream>>>(selbuf, selcnt, kyi, kxi, kval, out);
  orient_kernel<<<dim3(Kk,NSEG),dim3(64),0,stream>>>(img1, img2, kyi, kxi, wn, kth);
  bad_kernel<<<dim3(Kk,NSEG),dim3(256),0,stream>>>(img1, img2, offs, thrv, rad,
                                                   kyi, kxi, kval, kth, d1, d2, sq1, sq2);

  float* Zm=r0; float* Zt=r1;   // reuse stencil buffers (padded Z layout fits)
  dist_kernel<<<dim3(16,16,Bb),dim3(256),0,stream>>>(d1,d2,sq1,sq2,Zm,Zt);
  zborder_kernel<<<dim3((Bb*KP1+255)/256),dim3(256),0,stream>>>(Zm,Zt);
  hipMemsetAsync(uvec,0,(size_t)Bb*ZLD*4,stream);
  hipMemsetAsync(vvec,0,(size_t)Bb*ZLD*4,stream);
  for(int it=0; it<20; ++it){
    sink_lse<<<dim3((Bb*KP1+3)/4),dim3(256),0,stream>>>(Zm, vvec, uvec);
    sink_lse<<<dim3((Bb*KP1+3)/4),dim3(256),0,stream>>>(Zt, uvec, vvec);
  }
  size_t tot=(size_t)Bb*KP1*KP1;
  probs_kernel<<<dim3((u32)((tot+255)/256)),dim3(256),0,stream>>>(Zm, uvec, vvec, out + (size_t)2*Bb*Kk*2);
}

// Round 7
// 655.729 us; speedup vs baseline: 1.5087x; 1.0949x over previous
//
#include <hip/hip_runtime.h>
#include <hip/hip_fp16.h>
#include <math.h>

typedef unsigned long long u64;
typedef unsigned int u32;

#define Hh 960
#define Ww 1280
#define Bb 2
#define Kk 1024
#define Pp 256
#define KP1 1025
#define NSEG 4
#define LISTCAP 131072
#define PR 28
#define PS 57
#define ZLD 1040                         /* padded Z row stride (16B-aligned) */
static const size_t ZB = (size_t)KP1*ZLD;  // per-batch Z floats

static const size_t HWp = (size_t)Hh * Ww;   // one plane
static const size_t PLn = HWp * Bb;          // B planes

#define TAUf 0.2f
#define NMS_EPS 1e-7f
#define DET_T 0.001f
#define NORMV (-7.6246189861593985f)   /* -log(2*K) */
#define LOGKV (6.9314718055994531f)    /* log(K) */

__constant__ float WR[6] = {1.0f, 1.0f/9.0f, 1.0f/25.0f, 1.0f/49.0f, 1.0f/81.0f, 1.0f/121.0f};

__device__ __forceinline__ int imin(int a,int b){return a<b?a:b;}
__device__ __forceinline__ int imax(int a,int b){return a>b?a:b;}

// ---------------- FED diffusion step (fused: Sobel->g->flux) ----------------
__global__ __launch_bounds__(256) void fed_step(const float* __restrict__ src, float* __restrict__ dst){
  __shared__ float Lt[36][37];
  __shared__ float Gt[34][35];
  const int bx = blockIdx.x*32, by = blockIdx.y*32, b = blockIdx.z;
  const float* S = src + (size_t)b*HWp;
  float* D = dst + (size_t)b*HWp;
  const int t = threadIdx.y*32 + threadIdx.x;
  for (int i=t;i<36*36;i+=256){
    int ly=i/36, lx=i-ly*36;
    int gy=by+ly-2, gx=bx+lx-2;
    Lt[ly][lx] = (gy>=0 && gy<Hh && gx>=0 && gx<Ww) ? S[(size_t)gy*Ww+gx] : 0.0f;  // zero-pad for Sobel
  }
  __syncthreads();
  const float k2 = (float)(0.05*0.05);
  for (int i=t;i<34*34;i+=256){
    int ly=i/34, lx=i-ly*34;
    int Ly=ly+1, Lx=lx+1;
    float sx = (-Lt[Ly-1][Lx-1]+Lt[Ly-1][Lx+1]
                -2.0f*Lt[Ly][Lx-1]+2.0f*Lt[Ly][Lx+1]
                -Lt[Ly+1][Lx-1]+Lt[Ly+1][Lx+1])*0.125f;
    float sy = (-Lt[Ly-1][Lx-1]-2.0f*Lt[Ly-1][Lx]-Lt[Ly-1][Lx+1]
                +Lt[Ly+1][Lx-1]+2.0f*Lt[Ly+1][Lx]+Lt[Ly+1][Lx+1])*0.125f;
    Gt[ly][lx] = 1.0f/(1.0f + (sx*sx+sy*sy)/k2);
  }
  __syncthreads();
  for (int r=0;r<4;++r){
    int oy=threadIdx.y + r*8, ox=threadIdx.x;
    int gy=by+oy, gx=bx+ox;
    if (gy>=Hh || gx>=Ww) continue;
    int gyn=imax(gy-1,0), gys=imin(gy+1,Hh-1), gxw=imax(gx-1,0), gxe=imin(gx+1,Ww-1);
    float Lc=Lt[oy+2][ox+2];
    float Ln=Lt[gyn-by+2][ox+2];
    float Ls=Lt[gys-by+2][ox+2];
    float Lw=Lt[oy+2][gxw-bx+2];
    float Le=Lt[oy+2][gxe-bx+2];
    float gc=Gt[oy+1][ox+1];
    float gn=Gt[gyn-by+1][ox+1];
    float gs=Gt[gys-by+1][ox+1];
    float gw=Gt[oy+1][gxw-bx+1];
    float ge=Gt[oy+1][gxe-bx+1];
    float flux = 0.5f*((gc+gn)*(Ln-Lc) + (gc+gs)*(Ls-Lc) + (gc+gw)*(Lw-Lc) + (gc+ge)*(Le-Lc));
    D[(size_t)gy*Ww+gx] = Lc + TAUf*flux;
  }
}

// ---------------- Hessian response (Lxx*Lyy - Lxy^2), resp = max(resp, det) ----------------
__global__ __launch_bounds__(256) void response_kernel(const float* __restrict__ src, float* __restrict__ resp, int first){
  __shared__ float Lt[36][37];
  __shared__ float Sx[34][35];
  const int bx = blockIdx.x*32, by = blockIdx.y*32, b = blockIdx.z;
  const float* S = src + (size_t)b*HWp;
  float* R = resp + (size_t)b*HWp;
  const int t = threadIdx.y*32 + threadIdx.x;
  for (int i=t;i<36*36;i+=256){
    int ly=i/36, lx=i-ly*36;
    int gy=by+ly-2, gx=bx+lx-2;
    Lt[ly][lx] = (gy>=0 && gy<Hh && gx>=0 && gx<Ww) ? S[(size_t)gy*Ww+gx] : 0.0f;
  }
  __syncthreads();
  for (int i=t;i<34*34;i+=256){
    int ly=i/34, lx=i-ly*34;
    int gy=by+ly-1, gx=bx+lx-1;
    float v=0.0f;
    if (gy>=0 && gy<Hh && gx>=0 && gx<Ww){
      int Ly=ly+1, Lx=lx+1;
      v = (-Lt[Ly-1][Lx-1]+Lt[Ly-1][Lx+1]
           -2.0f*Lt[Ly][Lx-1]+2.0f*Lt[Ly][Lx+1]
           -Lt[Ly+1][Lx-1]+Lt[Ly+1][Lx+1])*0.125f;
    }
    Sx[ly][lx]=v;
  }
  __syncthreads();
  for (int r=0;r<4;++r){
    int oy=threadIdx.y + r*8, ox=threadIdx.x;
    int gy=by+oy, gx=bx+ox;
    if (gy>=Hh || gx>=Ww) continue;
    int Ly=oy+2, Lx=ox+2;
    float Lxx = Lt[Ly][Lx-1]-2.0f*Lt[Ly][Lx]+Lt[Ly][Lx+1];
    float Lyy = Lt[Ly-1][Lx]-2.0f*Lt[Ly][Lx]+Lt[Ly+1][Lx];
    int Sy=oy+1, Sxi=ox+1;
    float Lxy = (-Sx[Sy-1][Sxi-1]-2.0f*Sx[Sy-1][Sxi]-Sx[Sy-1][Sxi+1]
                 +Sx[Sy+1][Sxi-1]+2.0f*Sx[Sy+1][Sxi]+Sx[Sy+1][Sxi+1])*0.125f;
    float det = Lxx*Lyy - Lxy*Lxy;
    size_t id=(size_t)gy*Ww+gx;
    R[id] = first ? fmaxf(det,0.0f) : fmaxf(R[id], det);
  }
}

// ---------------- fused: threshold + separable 5x5 NMS + 7x7 NMS + block compaction ----------------
__global__ __launch_bounds__(256) void detect_compact(const float* __restrict__ resp,
                                                      u64* __restrict__ lists,
                                                      int* __restrict__ cnt, int segbase){
  const int TS=42;
  __shared__ float Tt[TS][TS+1];   // thresholded response, halo 5
  __shared__ float H5[TS][40];     // horizontal 5-max (center x+2), cols 0..37
  __shared__ float Ss[38][39];     // 5x5-NMS-masked, halo 3
  __shared__ u64 keys[1024];
  __shared__ int lcnt, gbase;
  const int bx = blockIdx.x*32, by = blockIdx.y*32, b = blockIdx.z;
  const float* S = resp + (size_t)b*HWp;
  const int t = threadIdx.y*32 + threadIdx.x;
  if (t==0) lcnt=0;
  for (int i=t;i<TS*TS;i+=256){
    int ly=i/TS, lx=i-ly*TS;
    int gy=by+ly-5, gx=bx+lx-5;
    float v = (gy>=0 && gy<Hh && gx>=0 && gx<Ww) ? S[(size_t)gy*Ww+gx] : 0.0f;
    Tt[ly][lx] = (v>DET_T) ? v : 0.0f;
  }
  __syncthreads();
  // separable 5x5 max: horizontal pass (42 rows x 38 cols)
  for (int i=t;i<42*38;i+=256){
    int y=i/38, x=i-(i/38)*38;
    float m=Tt[y][x];
    m=fmaxf(m,Tt[y][x+1]); m=fmaxf(m,Tt[y][x+2]);
    m=fmaxf(m,Tt[y][x+3]); m=fmaxf(m,Tt[y][x+4]);
    H5[y][x]=m;
  }
  __syncthreads();
  // vertical pass + mask (38x38)
  for (int i=t;i<38*38;i+=256){
    int y=i/38, x=i-(i/38)*38;
    float m=H5[y][x];
    m=fmaxf(m,H5[y+1][x]); m=fmaxf(m,H5[y+2][x]);
    m=fmaxf(m,H5[y+3][x]); m=fmaxf(m,H5[y+4][x]);
    float c=Tt[y+2][x+2];
    Ss[y][x]=(c>=m-NMS_EPS)?c:0.0f;
  }
  __syncthreads();
  const int seg=segbase+b;
  for (int r=0;r<4;++r){
    int oy=threadIdx.y + r*8, ox=threadIdx.x;
    int gy=by+oy, gx=bx+ox;
    bool pos=false; u64 key=0;
    if (gy<Hh && gx<Ww){
      float v=Ss[oy+3][ox+3];
      if (v>0.0f){
        float m=0.0f;
        #pragma unroll
        for(int dy=0;dy<7;dy++)
          #pragma unroll
          for(int dx=0;dx<7;dx++)
            m=fmaxf(m,Ss[oy+dy][ox+dx]);
        if (v>=m-NMS_EPS){
          u32 idx=(u32)(gy*Ww+gx);
          key=((u64)__float_as_uint(v)<<32)|(u64)(0xFFFFFFFFu-idx);
          pos=true;
        }
      }
    }
    u64 mask=__ballot(pos);
    if (mask){
      int lane=t&63;
      int leader=__ffsll((long long)mask)-1;
      int base=0;
      if (lane==leader) base=atomicAdd(&lcnt,__popcll(mask));
      base=__shfl(base,leader);
      if (pos){
        int rk=__popcll(mask & ((1ULL<<lane)-1ULL));
        keys[base+rk]=key;
      }
    }
  }
  __syncthreads();
  if (t==0 && lcnt>0) gbase=atomicAdd(&cnt[seg*64], lcnt);
  __syncthreads();
  int n=lcnt;
  for (int i=t;i<n;i+=256){
    int p=gbase+i;
    if (p<LISTCAP) lists[(size_t)seg*LISTCAP+p]=keys[i];
  }
}

// ---------------- per-seg spin barrier (8 blocks per seg; agent-scope) ----------------
__device__ __forceinline__ void segbar(int* bar, int* gen, int seg, int target){
  __syncthreads();
  if(threadIdx.x==0){
    __threadfence();
    int old=atomicAdd(&bar[seg*16],1);
    if(old==7){
      atomicExch(&bar[seg*16],0);
      atomicAdd(&gen[seg*16],1);
    } else {
      while(__hip_atomic_load(&gen[seg*16],__ATOMIC_ACQUIRE,__HIP_MEMORY_SCOPE_AGENT)<target){
        __builtin_amdgcn_s_sleep(8);
      }
    }
    __threadfence();
  }
  __syncthreads();
}

// ---------------- fused radix-select top-K (8 rounds) + gather, one launch ----------------
// grid (8, NSEG); all cross-block state reads via agent-scope atomic loads (L1 bypass).
__global__ __launch_bounds__(256) void topk_all(const u64* __restrict__ lists, const int* __restrict__ cnt,
                          u32* __restrict__ ghist, int* __restrict__ krem, int* __restrict__ takeAll,
                          u64* __restrict__ prefix, u64* __restrict__ Tf,
                          u64* __restrict__ selbuf, int* __restrict__ selcnt,
                          int* __restrict__ bar, int* __restrict__ gen){
  const int seg=blockIdx.y, bid=blockIdx.x, tid=threadIdx.x;
  __shared__ u32 h[256];
  __shared__ int tash;
  __shared__ u64 pfxsh;
  const int n=imin(cnt[seg*64],LISTCAP);
  const u64* L=lists+(size_t)seg*LISTCAP;
  int target=0;
  for(int rd=0;rd<8;rd++){
    if(tid==0){
      tash=(rd>0)?__hip_atomic_load(&takeAll[seg],__ATOMIC_RELAXED,__HIP_MEMORY_SCOPE_AGENT):0;
      pfxsh=(rd>0)?__hip_atomic_load(&prefix[seg],__ATOMIC_RELAXED,__HIP_MEMORY_SCOPE_AGENT):0ULL;
    }
    h[tid]=0;
    __syncthreads();
    if(!tash){
      int shift=56-8*rd;
      u64 maskHi=(rd==0)?0ULL:(~0ULL<<(shift+8));
      u64 pfx=pfxsh;
      for(int i=bid*256+tid;i<n;i+=8*256){
        u64 k=L[i];
        if((k&maskHi)==pfx) atomicAdd(&h[(int)((k>>shift)&255ULL)],1u);
      }
      __syncthreads();
      if(h[tid]) atomicAdd(&ghist[seg*256+tid],h[tid]);
    }
    segbar(bar,gen,seg,++target);
    if(bid==0){
      h[tid]=__hip_atomic_load(&ghist[seg*256+tid],__ATOMIC_RELAXED,__HIP_MEMORY_SCOPE_AGENT);
      __syncthreads();
      if(tid==0){
        if(rd==0){
          krem[seg]=Kk;
          __hip_atomic_store(&prefix[seg],0ULL,__ATOMIC_RELEASE,__HIP_MEMORY_SCOPE_AGENT);
          __hip_atomic_store(&takeAll[seg],(n<=Kk)?1:0,__ATOMIC_RELEASE,__HIP_MEMORY_SCOPE_AGENT);
        }
        int taNow=__hip_atomic_load(&takeAll[seg],__ATOMIC_RELAXED,__HIP_MEMORY_SCOPE_AGENT);
        if(taNow){
          if(rd==7) __hip_atomic_store(&Tf[seg],1ULL,__ATOMIC_RELEASE,__HIP_MEMORY_SCOPE_AGENT);
        } else {
          int kr=krem[seg];
          int acc=0,b2=255;
          for(;b2>0;--b2){ int c2=(int)h[b2]; if(acc+c2>=kr) break; acc+=c2; }
          int shift=56-8*rd;
          u64 pf=__hip_atomic_load(&prefix[seg],__ATOMIC_RELAXED,__HIP_MEMORY_SCOPE_AGENT);
          pf|=((u64)(u32)b2)<<shift;
          __hip_atomic_store(&prefix[seg],pf,__ATOMIC_RELEASE,__HIP_MEMORY_SCOPE_AGENT);
          krem[seg]=kr-acc;
          if(rd==7) __hip_atomic_store(&Tf[seg],pf,__ATOMIC_RELEASE,__HIP_MEMORY_SCOPE_AGENT);
        }
      }
      __syncthreads();
      ghist[seg*256+tid]=0u;
    }
    segbar(bar,gen,seg,++target);
  }
  // gather
  u64 T=__hip_atomic_load(&Tf[seg],__ATOMIC_RELAXED,__HIP_MEMORY_SCOPE_AGENT);
  for(int i0=bid*256;i0<n;i0+=8*256){
    int i=i0+tid;
    bool sel=false; u64 k=0;
    if(i<n){ k=L[i]; sel=(k>=T); }
    u64 mask=__ballot(sel);
    if(mask){
      int lane=tid&63;
      int leader=__ffsll((long long)mask)-1;
      int base=0;
      if(lane==leader) base=atomicAdd(&selcnt[seg*64],__popcll(mask));
      base=__shfl(base,leader);
      if(sel){
        int p=base+__popcll(mask & ((1ULL<<lane)-1ULL));
        if(p<Kk) selbuf[(size_t)seg*Kk+p]=k;
      }
    }
  }
}

// ---------------- sort 1024 keys desc, emit keypoint meta + k1/k2 ----------------
__global__ __launch_bounds__(1024) void finalize_kernel(const u64* __restrict__ selbuf, const int* __restrict__ selcnt,
                                int* __restrict__ kyi, int* __restrict__ kxi, float* __restrict__ kval,
                                float* __restrict__ outp){
  int seg=blockIdx.x, tid=threadIdx.x;
  __shared__ u64 a[1024];
  int n=selcnt[seg*64]; if(n>Kk)n=Kk;
  a[tid]=(tid<n)?selbuf[(size_t)seg*Kk+tid]:0ULL;
  __syncthreads();
  for(int k=2;k<=1024;k<<=1){
    for(int j=k>>1;j>0;j>>=1){
      int ixj=tid^j;
      if(ixj>tid){
        u64 x=a[tid], y=a[ixj];
        bool desc=((tid&k)==0);
        if(desc ? (x<y) : (x>y)){ a[tid]=y; a[ixj]=x; }
      }
      __syncthreads();
    }
  }
  u64 key=a[tid];
  bool val=(key!=0ULL);
  u32 idx=0xFFFFFFFFu-(u32)(key&0xFFFFFFFFULL);
  int y= val ? (int)(idx/Ww) : 0;
  int x= val ? (int)(idx%Ww) : 0;
  int mi=seg*Kk+tid;
  kyi[mi]=y; kxi[mi]=x; kval[mi]= val?1.0f:0.0f;
  int imi=seg>>1, bb=seg&1;
  float* ko=outp + (size_t)imi*(Bb*Kk*2) + ((size_t)bb*Kk+tid)*2;
  ko[0]= val ? (float)y : -1.0f;
  ko[1]= val ? (float)x : -1.0f;
}

// ---------------- Gaussian weights (1D, normalized) ----------------
__global__ void init_weights(float* wn){
  if(threadIdx.x==0 && blockIdx.x==0){
    double w[15]; double S=0.0;
    for(int i=0;i<15;i++){ double c=(double)i-7.0; w[i]=exp(-(c*c)/(2.0*2.5*2.5)); S+=w[i]; }
    for(int i=0;i<15;i++) wn[i]=(float)(w[i]/S);
  }
}

__device__ __forceinline__ float ldz(const float* __restrict__ img,int y,int x){
  return (y>=0&&y<Hh&&x>=0&&x<Ww)?img[(size_t)y*Ww+x]:0.0f;
}

// ---------------- per-keypoint orientation (15x15 Gaussian-weighted Sobel) ----------------
__global__ __launch_bounds__(64) void orient_kernel(const float* __restrict__ img1, const float* __restrict__ img2,
                              const int* __restrict__ kyi, const int* __restrict__ kxi,
                              const float* __restrict__ wn, float* __restrict__ kth){
  int seg=blockIdx.y, ki=blockIdx.x, lane=threadIdx.x;
  __shared__ float w15[15];
  if(lane<15) w15[lane]=wn[lane];
  __syncthreads();
  const float* img=(seg<2?img1:img2)+(size_t)(seg&1)*HWp;
  int mi=seg*Kk+ki;
  int yc=kyi[mi], xc=kxi[mi];
  float ax=0.0f, ay=0.0f;
  for(int tp=lane;tp<225;tp+=64){
    int du=tp/15-7, dv=tp-(tp/15)*15-7;
    int yy=yc+du, xx=xc+dv;
    if(yy<0||yy>=Hh||xx<0||xx>=Ww) continue;
    float p00=ldz(img,yy-1,xx-1), p01=ldz(img,yy-1,xx), p02=ldz(img,yy-1,xx+1);
    float p10=ldz(img,yy,xx-1),                          p12=ldz(img,yy,xx+1);
    float p20=ldz(img,yy+1,xx-1), p21=ldz(img,yy+1,xx), p22=ldz(img,yy+1,xx+1);
    float sx=(-p00+p02-2.0f*p10+2.0f*p12-p20+p22)*0.125f;
    float sy=(-p00-2.0f*p01-p02+p20+2.0f*p21+p22)*0.125f;
    float wgt=w15[du+7]*w15[dv+7];
    ax=fmaf(wgt,sx,ax); ay=fmaf(wgt,sy,ay);
  }
  for(int o=32;o;o>>=1){ ax+=__shfl_down(ax,o); ay+=__shfl_down(ay,o); }
  if(lane==0) kth[mi]=atan2f(ay,ax);
}

// ---------------- BAD descriptor: LDS summed-area table + 4-corner box sums ----------------
__global__ __launch_bounds__(256) void bad_kernel(const float* __restrict__ img1, const float* __restrict__ img2,
                           const float* __restrict__ offs, const float* __restrict__ thrv,
                           const int* __restrict__ rad,
                           const int* __restrict__ kyi, const int* __restrict__ kxi,
                           const float* __restrict__ kval, const float* __restrict__ kth,
                           float* __restrict__ d1, float* __restrict__ d2,
                           float* __restrict__ sq1, float* __restrict__ sq2){
  __shared__ float sat[PS+1][PS+2];
  __shared__ float sm[4];
  __shared__ float nsh;
  int seg=blockIdx.y, ki=blockIdx.x, p=threadIdx.x;
  const float* img=(seg<2?img1:img2)+(size_t)(seg&1)*HWp;
  int mi=seg*Kk+ki;
  int yci=kyi[mi], xci=kxi[mi];
  for (int i=p;i<PS+1;i+=256){ sat[0][i]=0.0f; sat[i][0]=0.0f; }
  if (p==0) sat[0][PS]=0.0f;
  for (int i=p;i<PS*PS;i+=256){
    int ly=i/PS, lx=i-ly*PS;
    int gy=yci-PR+ly, gx=xci-PR+lx;
    sat[ly+1][lx+1]=(gy>=0&&gy<Hh&&gx>=0&&gx<Ww)?img[(size_t)gy*Ww+gx]:0.0f;
  }
  __syncthreads();
  if (p<PS){
    float run=0.0f;
    for(int x=1;x<=PS;x++){ run+=sat[p+1][x]; sat[p+1][x]=run; }
  }
  __syncthreads();
  if (p<PS){
    float run=0.0f;
    for(int y=1;y<=PS;y++){ run+=sat[y][p+1]; sat[y][p+1]=run; }
  }
  __syncthreads();
  float yc=(float)yci, xc=(float)xci;
  float th=kth[mi];
  float c=cosf(th), s=sinf(th);
  float ox1=offs[p*4+0], oy1=offs[p*4+1], ox2=offs[p*4+2], oy2=offs[p*4+3];
  int r=rad[p];
  float w=WR[r];
  float px1=xc+c*ox1-s*oy1, py1=yc+s*ox1+c*oy1;
  float px2=xc+c*ox2-s*oy2, py2=yc+s*ox2+c*oy2;
  auto boxl=[&](float px,float py,int r_)->float{
    float rx=rintf(px), ry=rintf(py);
    int xi=(int)fminf(fmaxf(rx,0.0f),(float)(Ww-1));
    int yi=(int)fminf(fmaxf(ry,0.0f),(float)(Hh-1));
    int lx=xi-(xci-PR), ly=yi-(yci-PR);
    int y2=ly+r_+1, y1=ly-r_, x2=lx+r_+1, x1=lx-r_;
    return sat[y2][x2]-sat[y1][x2]-sat[y2][x1]+sat[y1][x1];
  };
  float s1=boxl(px1,py1,r)*w;
  float s2=boxl(px2,py2,r)*w;
  float v=(s1-s2-thrv[p])*kval[mi];
  float t=v*v;
  for(int o=32;o;o>>=1) t+=__shfl_down(t,o);
  if((p&63)==0) sm[p>>6]=t;
  __syncthreads();
  if(p==0) nsh=sqrtf(sm[0]+sm[1]+sm[2]+sm[3]);
  __syncthreads();
  float dv=v/(nsh+1e-8f);
  float* dd=(seg<2?d1:d2);
  dd[((size_t)(seg&1)*Kk+ki)*Pp+p]=dv;
  float t2=dv*dv;
  for(int o=32;o;o>>=1) t2+=__shfl_down(t2,o);
  __syncthreads();
  if((p&63)==0) sm[p>>6]=t2;
  __syncthreads();
  if(p==0){ float* sq=(seg<2?sq1:sq2); sq[(size_t)(seg&1)*Kk+ki]=sm[0]+sm[1]+sm[2]+sm[3]; }
}

// ---------------- pairwise distance -> Z (padded stride, and transposed copy) ----------------
__global__ __launch_bounds__(256) void dist_kernel(const float* __restrict__ d1, const float* __restrict__ d2,
                            const float* __restrict__ sq1, const float* __restrict__ sq2,
                            float* __restrict__ Zm, float* __restrict__ Zt){
  int b=blockIdx.z;
  int i0=blockIdx.y*64, j0=blockIdx.x*64;
  int tid=threadIdx.x;
  int tx=tid&15, ty=tid>>4;
  __shared__ float Ast[64][68], Bst[64][68];
  const float* D1=d1+(size_t)b*Kk*Pp;
  const float* D2=d2+(size_t)b*Kk*Pp;
  float acc[4][4]={};
  for(int p0=0;p0<Pp;p0+=64){
    for(int i=tid;i<64*16;i+=256){
      int row=i>>4, c4=(i&15)<<2;
      float4 va=*reinterpret_cast<const float4*>(&D1[(size_t)(i0+row)*Pp+p0+c4]);
      float4 vb=*reinterpret_cast<const float4*>(&D2[(size_t)(j0+row)*Pp+p0+c4]);
      Ast[c4+0][row]=va.x; Ast[c4+1][row]=va.y; Ast[c4+2][row]=va.z; Ast[c4+3][row]=va.w;
      Bst[c4+0][row]=vb.x; Bst[c4+1][row]=vb.y; Bst[c4+2][row]=vb.z; Bst[c4+3][row]=vb.w;
    }
    __syncthreads();
    #pragma unroll 8
    for(int kk=0;kk<64;++kk){
      float4 av=*reinterpret_cast<const float4*>(&Ast[kk][ty*4]);
      float4 bv=*reinterpret_cast<const float4*>(&Bst[kk][tx*4]);
      acc[0][0]=fmaf(av.x,bv.x,acc[0][0]); acc[0][1]=fmaf(av.x,bv.y,acc[0][1]);
      acc[0][2]=fmaf(av.x,bv.z,acc[0][2]); acc[0][3]=fmaf(av.x,bv.w,acc[0][3]);
      acc[1][0]=fmaf(av.y,bv.x,acc[1][0]); acc[1][1]=fmaf(av.y,bv.y,acc[1][1]);
      acc[1][2]=fmaf(av.y,bv.z,acc[1][2]); acc[1][3]=fmaf(av.y,bv.w,acc[1][3]);
      acc[2][0]=fmaf(av.z,bv.x,acc[2][0]); acc[2][1]=fmaf(av.z,bv.y,acc[2][1]);
      acc[2][2]=fmaf(av.z,bv.z,acc[2][2]); acc[2][3]=fmaf(av.z,bv.w,acc[2][3]);
      acc[3][0]=fmaf(av.w,bv.x,acc[3][0]); acc[3][1]=fmaf(av.w,bv.y,acc[3][1]);
      acc[3][2]=fmaf(av.w,bv.z,acc[3][2]); acc[3][3]=fmaf(av.w,bv.w,acc[3][3]);
    }
    __syncthreads();
  }
  int gi=i0+ty*4, gj=j0+tx*4;
  float si[4], sj[4];
  #pragma unroll
  for(int i=0;i<4;i++){ si[i]=sq1[b*Kk+gi+i]; sj[i]=sq2[b*Kk+gj+i]; }
  #pragma unroll
  for(int i=0;i<4;i++){
    #pragma unroll
    for(int j=0;j<4;j++){
      float dd=si[i]+sj[j]-2.0f*acc[i][j];
      float dist=sqrtf(fmaxf(dd,0.0f)+1e-12f);
      Zm[(size_t)b*ZB+(size_t)(gi+i)*ZLD+(gj+j)]=-dist;
      Zt[(size_t)b*ZB+(size_t)(gj+j)*ZLD+(gi+i)]=-dist;
    }
  }
}

// border (=1.0) + pad columns (=-1e30 so exp -> 0)
__global__ void zborder_kernel(float* __restrict__ Zm, float* __restrict__ Zt){
  int i=blockIdx.x*256+threadIdx.x;
  if(i>=Bb*KP1) return;
  int b=i/KP1, j=i-(i/KP1)*KP1;
  size_t base=(size_t)b*ZB;
  Zm[base+(size_t)j*ZLD+Kk]=1.0f;
  Zm[base+(size_t)Kk*ZLD+j]=1.0f;
  Zt[base+(size_t)j*ZLD+Kk]=1.0f;
  Zt[base+(size_t)Kk*ZLD+j]=1.0f;
  for(int c=KP1;c<ZLD;c++){
    Zm[base+(size_t)j*ZLD+c]=-1.0e30f;
    Zt[base+(size_t)j*ZLD+c]=-1.0e30f;
  }
}

// ---------------- precompute E = exp(Z) in fp16 (pads -> 0) ----------------
__global__ void expz_kernel(const float* __restrict__ Zm, const float* __restrict__ Zt,
                            __half* __restrict__ Em, __half* __restrict__ Et){
  size_t q=(size_t)blockIdx.x*256+threadIdx.x;
  const size_t tot4=(size_t)Bb*ZB/4;
  if(q>=2*tot4) return;
  const float* src=(q<tot4)?Zm:Zt;
  __half* dst=(q<tot4)?Em:Et;
  size_t j=(q<tot4)?q:q-tot4;
  float4 z=reinterpret_cast<const float4*>(src)[j];
  __half2 a=__floats2half2_rn(expf(z.x),expf(z.y));
  __half2 b=__floats2half2_rn(expf(z.z),expf(z.w));
  reinterpret_cast<__half2*>(dst)[2*j]=a;
  reinterpret_cast<__half2*>(dst)[2*j+1]=b;
}

// ev = exp(v=0) = 1 on valid cols, 0 on pads; eu zeroed
__global__ void init_euv(float* __restrict__ euv, float* __restrict__ evv){
  int i=blockIdx.x*256+threadIdx.x;
  if(i>=Bb*ZLD) return;
  int j=i-(i/ZLD)*ZLD;
  evv[i]=(j<KP1)?1.0f:0.0f;
  euv[i]=0.0f;
}

// ---------------- Sinkhorn half-iteration as fp16 GEMV: eu = elm / (E @ ev); u = lm - log(s) ----------------
struct H4{ __half2 a, b; };
__global__ __launch_bounds__(256) void sink_gemv(const __half* __restrict__ E,
        const float* __restrict__ evin, float* __restrict__ euout, float* __restrict__ uout){
  int row=blockIdx.x*4+(threadIdx.x>>6);
  if(row>=Bb*KP1) return;
  int b=row/KP1, i=row-b*KP1;
  int lane=threadIdx.x&63;
  const H4* e4=reinterpret_cast<const H4*>(E+((size_t)b*KP1+i)*ZLD);
  const float4* v4=reinterpret_cast<const float4*>(evin+(size_t)b*ZLD);
  float s=0.0f;
  for(int j=lane;j<ZLD/4;j+=64){
    H4 e=e4[j]; float4 v=v4[j];
    float2 ea=__half22float2(e.a), eb=__half22float2(e.b);
    s=fmaf(ea.x,v.x,s); s=fmaf(ea.y,v.y,s);
    s=fmaf(eb.x,v.z,s); s=fmaf(eb.y,v.w,s);
  }
  for(int o=32;o;o>>=1) s+=__shfl_down(s,o);
  if(lane==0){
    float lm,elm;
    if(i<Kk){ lm=NORMV; elm=4.8828125e-4f; }       // exp(-log 2K) = 1/2048 exact
    else    { lm=LOGKV+NORMV; elm=0.5f; }          // K/(2K) exact
    euout[(size_t)b*ZLD+i]=elm/s;
    uout [(size_t)b*ZLD+i]=lm-logf(s);
  }
}

// ---------------- final probs = exp(Z+u+v-norm) ----------------
__global__ void probs_kernel(const float* __restrict__ Zm, const float* __restrict__ uu,
                             const float* __restrict__ vv, float* __restrict__ outp){
  size_t i=(size_t)blockIdx.x*256+threadIdx.x;
  const size_t tot=(size_t)Bb*KP1*KP1;
  if(i>=tot) return;
  size_t b=i/((size_t)KP1*KP1);
  size_t rem=i-b*(size_t)KP1*KP1;
  int rr=(int)(rem/KP1), cc=(int)(rem-(size_t)(rem/KP1)*KP1);
  outp[i]=expf(Zm[b*ZB+(size_t)rr*ZLD+cc]+uu[b*ZLD+rr]+vv[b*ZLD+cc]-NORMV);
}

extern "C" void kernel_launch(void* const* d_in, const int* in_sizes, int n_in,
                              void* d_out, int out_size, void* d_ws, size_t ws_size,
                              hipStream_t stream) {
  (void)in_sizes; (void)n_in; (void)out_size;
  const float* img1=(const float*)d_in[0];
  const float* img2=(const float*)d_in[1];
  const float* offs=(const float*)d_in[2];
  const float* thrv=(const float*)d_in[3];
  const int*   rad =(const int*)d_in[4];
  float* out=(float*)d_out;

  const bool batched = ws_size >= ((size_t)72<<20);
  const int NP = batched ? 4 : 2;
  const size_t PB = HWp*(size_t)NP*4;

  char* wp=(char*)d_ws;
  auto carve=[&](size_t bytes)->char*{ char* p=wp; wp += (bytes+255)&~(size_t)255; return p; };
  float* r0  =(float*)carve(PB);               // L ping / Zm
  float* r1  =(float*)carve(PB);               // L pong / Zt
  float* resp=(float*)carve(PB);               // resp / Em,Et (fp16, 8.6MB total)
  u64*  lists=(u64*)carve((size_t)NSEG*LISTCAP*8);
  char* stateblk = carve(8192);
  int* cnt     =(int*)(stateblk);              // [seg*64]
  int* selcnt  =(int*)(stateblk+1024);         // [seg*64]
  int* krem    =(int*)(stateblk+2048);
  int* takeAll =(int*)(stateblk+2112);
  u64* prefix  =(u64*)(stateblk+2176);
  u64* Tf      =(u64*)(stateblk+2240);
  u32* ghist   =(u32*)(stateblk+2304);         // 4KB
  int* bar     =(int*)(stateblk+6656);         // [seg*16]
  int* gen     =(int*)(stateblk+6912);         // [seg*16]
  u64* selbuf  =(u64*)carve((size_t)NSEG*Kk*8);
  int* kyi     =(int*)carve((size_t)NSEG*Kk*4);
  int* kxi     =(int*)carve((size_t)NSEG*Kk*4);
  float* kval  =(float*)carve((size_t)NSEG*Kk*4);
  float* kth   =(float*)carve((size_t)NSEG*Kk*4);
  float* d1    =(float*)carve((size_t)Bb*Kk*Pp*4);
  float* d2    =(float*)carve((size_t)Bb*Kk*Pp*4);
  float* sq1   =(float*)carve((size_t)Bb*Kk*4);
  float* sq2   =(float*)carve((size_t)Bb*Kk*4);
  float* uvec  =(float*)carve((size_t)Bb*ZLD*4);
  float* vvec  =(float*)carve((size_t)Bb*ZLD*4);
  float* euvec =(float*)carve((size_t)Bb*ZLD*4);
  float* evvec =(float*)carve((size_t)Bb*ZLD*4);
  float* wn    =(float*)carve(64);

  // E matrices overlay the (dead-after-detect) resp buffer
  const size_t EBYTES = ((size_t)Bb*ZB*2 + 255)&~(size_t)255;   // 4.27MB each
  __half* Em=(__half*)resp;
  __half* Et=(__half*)((char*)resp + EBYTES);

  hipMemsetAsync(stateblk, 0, 8192, stream);
  init_weights<<<1,32,0,stream>>>(wn);

  dim3 TB(32,8);
  if (batched){
    dim3 TG(Ww/32, Hh/32, 4);
    hipMemcpyAsync(r0,       img1, PLn*4, hipMemcpyDeviceToDevice, stream);
    hipMemcpyAsync(r0+2*HWp, img2, PLn*4, hipMemcpyDeviceToDevice, stream);
    float* cur=r0; float* oth=r1;
    for(int st=1; st<=9; ++st){
      fed_step<<<TG,TB,0,stream>>>(cur, oth);
      float* tp=cur; cur=oth; oth=tp;
      if(st%3==0) response_kernel<<<TG,TB,0,stream>>>(cur, resp, st==3);
    }
    detect_compact<<<TG,TB,0,stream>>>(resp, lists, cnt, 0);
  } else {
    dim3 TG(Ww/32, Hh/32, Bb);
    for(int im=0; im<2; ++im){
      const float* srcimg = (im==0)? img1 : img2;
      hipMemcpyAsync(r0, srcimg, PLn*4, hipMemcpyDeviceToDevice, stream);
      float* cur=r0; float* oth=r1;
      for(int st=1; st<=9; ++st){
        fed_step<<<TG,TB,0,stream>>>(cur, oth);
        float* tp=cur; cur=oth; oth=tp;
        if(st%3==0) response_kernel<<<TG,TB,0,stream>>>(cur, resp, st==3);
      }
      detect_compact<<<TG,TB,0,stream>>>(resp, lists, cnt, im*2);
    }
  }

  topk_all<<<dim3(8,NSEG),dim3(256),0,stream>>>(lists, cnt, ghist, krem, takeAll,
                                                prefix, Tf, selbuf, selcnt, bar, gen);
  finalize_kernel<<<NSEG,1024,0,stream>>>(selbuf, selcnt, kyi, kxi, kval, out);
  orient_kernel<<<dim3(Kk,NSEG),dim3(64),0,stream>>>(img1, img2, kyi, kxi, wn, kth);
  bad_kernel<<<dim3(Kk,NSEG),dim3(256),0,stream>>>(img1, img2, offs, thrv, rad,
                                                   kyi, kxi, kval, kth, d1, d2, sq1, sq2);

  float* Zm=r0; float* Zt=r1;
  dist_kernel<<<dim3(16,16,Bb),dim3(256),0,stream>>>(d1,d2,sq1,sq2,Zm,Zt);
  zborder_kernel<<<dim3((Bb*KP1+255)/256),dim3(256),0,stream>>>(Zm,Zt);
  {
    size_t tot4=(size_t)Bb*ZB/4;
    expz_kernel<<<dim3((u32)((2*tot4+255)/256)),dim3(256),0,stream>>>(Zm,Zt,Em,Et);
  }
  init_euv<<<dim3((Bb*ZLD+255)/256),dim3(256),0,stream>>>(euvec,evvec);
  for(int it=0; it<20; ++it){
    sink_gemv<<<dim3((Bb*KP1+3)/4),dim3(256),0,stream>>>(Em, evvec, euvec, uvec);
    sink_gemv<<<dim3((Bb*KP1+3)/4),dim3(256),0,stream>>>(Et, euvec, evvec, vvec);
  }
  size_t tot=(size_t)Bb*KP1*KP1;
  probs_kernel<<<dim3((u32)((tot+255)/256)),dim3(256),0,stream>>>(Zm, uvec, vvec, out + (size_t)2*Bb*Kk*2);
}

// Round 8
// 628.181 us; speedup vs baseline: 1.5749x; 1.0439x over previous
//
#include <hip/hip_runtime.h>
#include <hip/hip_fp16.h>
#include <math.h>

typedef unsigned long long u64;
typedef unsigned int u32;

#define Hh 960
#define Ww 1280
#define Bb 2
#define Kk 1024
#define Pp 256
#define KP1 1025
#define NSEG 4
#define LISTCAP 131072
#define PR 28
#define PS 57
#define ZLD 1040                         /* padded Z row stride (16B-aligned) */
static const size_t ZB = (size_t)KP1*ZLD;  // per-batch Z floats

static const size_t HWp = (size_t)Hh * Ww;   // one plane
static const size_t PLn = HWp * Bb;          // B planes

#define TAUf 0.2f
#define NMS_EPS 1e-7f
#define DET_T 0.001f
#define NORMV (-7.6246189861593985f)   /* -log(2*K) */
#define LOGKV (6.9314718055994531f)    /* log(K) */

__constant__ float WR[6] = {1.0f, 1.0f/9.0f, 1.0f/25.0f, 1.0f/49.0f, 1.0f/81.0f, 1.0f/121.0f};

__device__ __forceinline__ int imin(int a,int b){return a<b?a:b;}
__device__ __forceinline__ int imax(int a,int b){return a>b?a:b;}

// ---------------- FED diffusion step (fused: Sobel->g->flux) ----------------
__global__ __launch_bounds__(256) void fed_step(const float* __restrict__ src, float* __restrict__ dst){
  __shared__ float Lt[36][37];
  __shared__ float Gt[34][35];
  const int bx = blockIdx.x*32, by = blockIdx.y*32, b = blockIdx.z;
  const float* S = src + (size_t)b*HWp;
  float* D = dst + (size_t)b*HWp;
  const int t = threadIdx.y*32 + threadIdx.x;
  for (int i=t;i<36*36;i+=256){
    int ly=i/36, lx=i-ly*36;
    int gy=by+ly-2, gx=bx+lx-2;
    Lt[ly][lx] = (gy>=0 && gy<Hh && gx>=0 && gx<Ww) ? S[(size_t)gy*Ww+gx] : 0.0f;  // zero-pad for Sobel
  }
  __syncthreads();
  const float k2 = (float)(0.05*0.05);
  for (int i=t;i<34*34;i+=256){
    int ly=i/34, lx=i-ly*34;
    int Ly=ly+1, Lx=lx+1;
    float sx = (-Lt[Ly-1][Lx-1]+Lt[Ly-1][Lx+1]
                -2.0f*Lt[Ly][Lx-1]+2.0f*Lt[Ly][Lx+1]
                -Lt[Ly+1][Lx-1]+Lt[Ly+1][Lx+1])*0.125f;
    float sy = (-Lt[Ly-1][Lx-1]-2.0f*Lt[Ly-1][Lx]-Lt[Ly-1][Lx+1]
                +Lt[Ly+1][Lx-1]+2.0f*Lt[Ly+1][Lx]+Lt[Ly+1][Lx+1])*0.125f;
    Gt[ly][lx] = 1.0f/(1.0f + (sx*sx+sy*sy)/k2);
  }
  __syncthreads();
  for (int r=0;r<4;++r){
    int oy=threadIdx.y + r*8, ox=threadIdx.x;
    int gy=by+oy, gx=bx+ox;
    if (gy>=Hh || gx>=Ww) continue;
    int gyn=imax(gy-1,0), gys=imin(gy+1,Hh-1), gxw=imax(gx-1,0), gxe=imin(gx+1,Ww-1);
    float Lc=Lt[oy+2][ox+2];
    float Ln=Lt[gyn-by+2][ox+2];
    float Ls=Lt[gys-by+2][ox+2];
    float Lw=Lt[oy+2][gxw-bx+2];
    float Le=Lt[oy+2][gxe-bx+2];
    float gc=Gt[oy+1][ox+1];
    float gn=Gt[gyn-by+1][ox+1];
    float gs=Gt[gys-by+1][ox+1];
    float gw=Gt[oy+1][gxw-bx+1];
    float ge=Gt[oy+1][gxe-bx+1];
    float flux = 0.5f*((gc+gn)*(Ln-Lc) + (gc+gs)*(Ls-Lc) + (gc+gw)*(Lw-Lc) + (gc+ge)*(Le-Lc));
    D[(size_t)gy*Ww+gx] = Lc + TAUf*flux;
  }
}

// ---------------- Hessian response (Lxx*Lyy - Lxy^2), resp = max(resp, det) ----------------
__global__ __launch_bounds__(256) void response_kernel(const float* __restrict__ src, float* __restrict__ resp, int first){
  __shared__ float Lt[36][37];
  __shared__ float Sx[34][35];
  const int bx = blockIdx.x*32, by = blockIdx.y*32, b = blockIdx.z;
  const float* S = src + (size_t)b*HWp;
  float* R = resp + (size_t)b*HWp;
  const int t = threadIdx.y*32 + threadIdx.x;
  for (int i=t;i<36*36;i+=256){
    int ly=i/36, lx=i-ly*36;
    int gy=by+ly-2, gx=bx+lx-2;
    Lt[ly][lx] = (gy>=0 && gy<Hh && gx>=0 && gx<Ww) ? S[(size_t)gy*Ww+gx] : 0.0f;
  }
  __syncthreads();
  for (int i=t;i<34*34;i+=256){
    int ly=i/34, lx=i-ly*34;
    int gy=by+ly-1, gx=bx+lx-1;
    float v=0.0f;
    if (gy>=0 && gy<Hh && gx>=0 && gx<Ww){
      int Ly=ly+1, Lx=lx+1;
      v = (-Lt[Ly-1][Lx-1]+Lt[Ly-1][Lx+1]
           -2.0f*Lt[Ly][Lx-1]+2.0f*Lt[Ly][Lx+1]
           -Lt[Ly+1][Lx-1]+Lt[Ly+1][Lx+1])*0.125f;
    }
    Sx[ly][lx]=v;
  }
  __syncthreads();
  for (int r=0;r<4;++r){
    int oy=threadIdx.y + r*8, ox=threadIdx.x;
    int gy=by+oy, gx=bx+ox;
    if (gy>=Hh || gx>=Ww) continue;
    int Ly=oy+2, Lx=ox+2;
    float Lxx = Lt[Ly][Lx-1]-2.0f*Lt[Ly][Lx]+Lt[Ly][Lx+1];
    float Lyy = Lt[Ly-1][Lx]-2.0f*Lt[Ly][Lx]+Lt[Ly+1][Lx];
    int Sy=oy+1, Sxi=ox+1;
    float Lxy = (-Sx[Sy-1][Sxi-1]-2.0f*Sx[Sy-1][Sxi]-Sx[Sy-1][Sxi+1]
                 +Sx[Sy+1][Sxi-1]+2.0f*Sx[Sy+1][Sxi]+Sx[Sy+1][Sxi+1])*0.125f;
    float det = Lxx*Lyy - Lxy*Lxy;
    size_t id=(size_t)gy*Ww+gx;
    R[id] = first ? fmaxf(det,0.0f) : fmaxf(R[id], det);
  }
}

// ---------------- fused: threshold + separable 5x5 NMS + 7x7 NMS + block compaction ----------------
__global__ __launch_bounds__(256) void detect_compact(const float* __restrict__ resp,
                                                      u64* __restrict__ lists,
                                                      int* __restrict__ cnt, int segbase){
  const int TS=42;
  __shared__ float Tt[TS][TS+1];   // thresholded response, halo 5
  __shared__ float H5[TS][40];     // horizontal 5-max (center x+2), cols 0..37
  __shared__ float Ss[38][39];     // 5x5-NMS-masked, halo 3
  __shared__ u64 keys[1024];
  __shared__ int lcnt, gbase;
  const int bx = blockIdx.x*32, by = blockIdx.y*32, b = blockIdx.z;
  const float* S = resp + (size_t)b*HWp;
  const int t = threadIdx.y*32 + threadIdx.x;
  if (t==0) lcnt=0;
  for (int i=t;i<TS*TS;i+=256){
    int ly=i/TS, lx=i-ly*TS;
    int gy=by+ly-5, gx=bx+lx-5;
    float v = (gy>=0 && gy<Hh && gx>=0 && gx<Ww) ? S[(size_t)gy*Ww+gx] : 0.0f;
    Tt[ly][lx] = (v>DET_T) ? v : 0.0f;
  }
  __syncthreads();
  for (int i=t;i<42*38;i+=256){
    int y=i/38, x=i-(i/38)*38;
    float m=Tt[y][x];
    m=fmaxf(m,Tt[y][x+1]); m=fmaxf(m,Tt[y][x+2]);
    m=fmaxf(m,Tt[y][x+3]); m=fmaxf(m,Tt[y][x+4]);
    H5[y][x]=m;
  }
  __syncthreads();
  for (int i=t;i<38*38;i+=256){
    int y=i/38, x=i-(i/38)*38;
    float m=H5[y][x];
    m=fmaxf(m,H5[y+1][x]); m=fmaxf(m,H5[y+2][x]);
    m=fmaxf(m,H5[y+3][x]); m=fmaxf(m,H5[y+4][x]);
    float c=Tt[y+2][x+2];
    Ss[y][x]=(c>=m-NMS_EPS)?c:0.0f;
  }
  __syncthreads();
  const int seg=segbase+b;
  for (int r=0;r<4;++r){
    int oy=threadIdx.y + r*8, ox=threadIdx.x;
    int gy=by+oy, gx=bx+ox;
    bool pos=false; u64 key=0;
    if (gy<Hh && gx<Ww){
      float v=Ss[oy+3][ox+3];
      if (v>0.0f){
        float m=0.0f;
        #pragma unroll
        for(int dy=0;dy<7;dy++)
          #pragma unroll
          for(int dx=0;dx<7;dx++)
            m=fmaxf(m,Ss[oy+dy][ox+dx]);
        if (v>=m-NMS_EPS){
          u32 idx=(u32)(gy*Ww+gx);
          key=((u64)__float_as_uint(v)<<32)|(u64)(0xFFFFFFFFu-idx);
          pos=true;
        }
      }
    }
    u64 mask=__ballot(pos);
    if (mask){
      int lane=t&63;
      int leader=__ffsll((long long)mask)-1;
      int base=0;
      if (lane==leader) base=atomicAdd(&lcnt,__popcll(mask));
      base=__shfl(base,leader);
      if (pos){
        int rk=__popcll(mask & ((1ULL<<lane)-1ULL));
        keys[base+rk]=key;
      }
    }
  }
  __syncthreads();
  if (t==0 && lcnt>0) gbase=atomicAdd(&cnt[seg*64], lcnt);
  __syncthreads();
  int n=lcnt;
  for (int i=t;i<n;i+=256){
    int p=gbase+i;
    if (p<LISTCAP) lists[(size_t)seg*LISTCAP+p]=keys[i];
  }
}

// ---------------- single-block-per-seg radix-select top-K + gather ----------------
// grid(NSEG), 1024 threads. All state in LDS; only __syncthreads, no fences.
__global__ __launch_bounds__(1024) void topk_one(const u64* __restrict__ lists, const int* __restrict__ cnt,
                                                 u64* __restrict__ selbuf, int* __restrict__ selcnt){
  const int seg=blockIdx.x, tid=threadIdx.x;
  __shared__ u32 h[256];
  __shared__ u32 scan[256];
  __shared__ int krem_s, ta_s, bsel, lbase;
  __shared__ u64 pfx_s;
  const int n=imin(cnt[seg*64],LISTCAP);
  const u64* L=lists+(size_t)seg*LISTCAP;
  if(tid==0){ krem_s=Kk; pfx_s=0ULL; ta_s=(n<=Kk)?1:0; lbase=0; }
  __syncthreads();
  u64 T=1ULL;
  if(!ta_s){
    for(int rd=0;rd<8;rd++){
      int shift=56-8*rd;
      u64 maskHi=(rd==0)?0ULL:(~0ULL<<(shift+8));
      u64 pfx=pfx_s;
      if(tid<256) h[tid]=0;
      __syncthreads();
      for(int i=tid;i<n;i+=1024){
        u64 k=L[i];
        if((k&maskHi)==pfx) atomicAdd(&h[(int)((k>>shift)&255ULL)],1u);
      }
      __syncthreads();
      if(tid<256) scan[tid]=h[tid];
      __syncthreads();
      // suffix scan: scan[b] = sum_{j>=b} h[j]
      for(int off=1;off<256;off<<=1){
        u32 v=0;
        if(tid<256 && tid+off<256) v=scan[tid+off];
        __syncthreads();
        if(tid<256) scan[tid]+=v;
        __syncthreads();
      }
      // pick b = max{b : scan[b] >= krem}; scan is non-increasing so boundary is unique
      int kr=krem_s;
      if(tid<256){
        bool ge=(scan[tid]>=(u32)kr);
        bool geN=(tid<255)?(scan[tid+1]>=(u32)kr):false;
        if(ge && !geN) bsel=tid;
      }
      __syncthreads();
      if(tid==0){
        int b=bsel;
        int acc=(b<255)?(int)scan[b+1]:0;
        pfx_s |= ((u64)(u32)b)<<shift;
        krem_s = kr-acc;
      }
      __syncthreads();
    }
    T=pfx_s;
  }
  __syncthreads();
  // gather keys >= T (wave-aggregated LDS counter)
  for(int i0=0;i0<n;i0+=1024){
    int i=i0+tid;
    bool sel=false; u64 k=0;
    if(i<n){ k=L[i]; sel=(k>=T); }
    u64 mask=__ballot(sel);
    if(mask){
      int lane=tid&63;
      int leader=__ffsll((long long)mask)-1;
      int base=0;
      if(lane==leader) base=atomicAdd(&lbase,__popcll(mask));
      base=__shfl(base,leader);
      if(sel){
        int p=base+__popcll(mask & ((1ULL<<lane)-1ULL));
        if(p<Kk) selbuf[(size_t)seg*Kk+p]=k;
      }
    }
  }
  __syncthreads();
  if(tid==0) selcnt[seg*64]=imin(lbase,Kk);
}

// ---------------- sort 1024 keys desc, emit keypoint meta + k1/k2 ----------------
__global__ __launch_bounds__(1024) void finalize_kernel(const u64* __restrict__ selbuf, const int* __restrict__ selcnt,
                                int* __restrict__ kyi, int* __restrict__ kxi, float* __restrict__ kval,
                                float* __restrict__ outp){
  int seg=blockIdx.x, tid=threadIdx.x;
  __shared__ u64 a[1024];
  int n=selcnt[seg*64]; if(n>Kk)n=Kk;
  a[tid]=(tid<n)?selbuf[(size_t)seg*Kk+tid]:0ULL;
  __syncthreads();
  for(int k=2;k<=1024;k<<=1){
    for(int j=k>>1;j>0;j>>=1){
      int ixj=tid^j;
      if(ixj>tid){
        u64 x=a[tid], y=a[ixj];
        bool desc=((tid&k)==0);
        if(desc ? (x<y) : (x>y)){ a[tid]=y; a[ixj]=x; }
      }
      __syncthreads();
    }
  }
  u64 key=a[tid];
  bool val=(key!=0ULL);
  u32 idx=0xFFFFFFFFu-(u32)(key&0xFFFFFFFFULL);
  int y= val ? (int)(idx/Ww) : 0;
  int x= val ? (int)(idx%Ww) : 0;
  int mi=seg*Kk+tid;
  kyi[mi]=y; kxi[mi]=x; kval[mi]= val?1.0f:0.0f;
  int imi=seg>>1, bb=seg&1;
  float* ko=outp + (size_t)imi*(Bb*Kk*2) + ((size_t)bb*Kk+tid)*2;
  ko[0]= val ? (float)y : -1.0f;
  ko[1]= val ? (float)x : -1.0f;
}

// ---------------- Gaussian weights (1D, normalized) ----------------
__global__ void init_weights(float* wn){
  if(threadIdx.x==0 && blockIdx.x==0){
    double w[15]; double S=0.0;
    for(int i=0;i<15;i++){ double c=(double)i-7.0; w[i]=exp(-(c*c)/(2.0*2.5*2.5)); S+=w[i]; }
    for(int i=0;i<15;i++) wn[i]=(float)(w[i]/S);
  }
}

__device__ __forceinline__ float ldz(const float* __restrict__ img,int y,int x){
  return (y>=0&&y<Hh&&x>=0&&x<Ww)?img[(size_t)y*Ww+x]:0.0f;
}

// ---------------- per-keypoint orientation (15x15 Gaussian-weighted Sobel) ----------------
__global__ __launch_bounds__(64) void orient_kernel(const float* __restrict__ img1, const float* __restrict__ img2,
                              const int* __restrict__ kyi, const int* __restrict__ kxi,
                              const float* __restrict__ wn, float* __restrict__ kth){
  int seg=blockIdx.y, ki=blockIdx.x, lane=threadIdx.x;
  __shared__ float w15[15];
  if(lane<15) w15[lane]=wn[lane];
  __syncthreads();
  const float* img=(seg<2?img1:img2)+(size_t)(seg&1)*HWp;
  int mi=seg*Kk+ki;
  int yc=kyi[mi], xc=kxi[mi];
  float ax=0.0f, ay=0.0f;
  for(int tp=lane;tp<225;tp+=64){
    int du=tp/15-7, dv=tp-(tp/15)*15-7;
    int yy=yc+du, xx=xc+dv;
    if(yy<0||yy>=Hh||xx<0||xx>=Ww) continue;
    float p00=ldz(img,yy-1,xx-1), p01=ldz(img,yy-1,xx), p02=ldz(img,yy-1,xx+1);
    float p10=ldz(img,yy,xx-1),                          p12=ldz(img,yy,xx+1);
    float p20=ldz(img,yy+1,xx-1), p21=ldz(img,yy+1,xx), p22=ldz(img,yy+1,xx+1);
    float sx=(-p00+p02-2.0f*p10+2.0f*p12-p20+p22)*0.125f;
    float sy=(-p00-2.0f*p01-p02+p20+2.0f*p21+p22)*0.125f;
    float wgt=w15[du+7]*w15[dv+7];
    ax=fmaf(wgt,sx,ax); ay=fmaf(wgt,sy,ay);
  }
  for(int o=32;o;o>>=1){ ax+=__shfl_down(ax,o); ay+=__shfl_down(ay,o); }
  if(lane==0) kth[mi]=atan2f(ay,ax);
}

// ---------------- BAD descriptor: LDS summed-area table + 4-corner box sums ----------------
__global__ __launch_bounds__(256) void bad_kernel(const float* __restrict__ img1, const float* __restrict__ img2,
                           const float* __restrict__ offs, const float* __restrict__ thrv,
                           const int* __restrict__ rad,
                           const int* __restrict__ kyi, const int* __restrict__ kxi,
                           const float* __restrict__ kval, const float* __restrict__ kth,
                           float* __restrict__ d1, float* __restrict__ d2,
                           float* __restrict__ sq1, float* __restrict__ sq2){
  __shared__ float sat[PS+1][PS+2];
  __shared__ float sm[4];
  __shared__ float nsh;
  int seg=blockIdx.y, ki=blockIdx.x, p=threadIdx.x;
  const float* img=(seg<2?img1:img2)+(size_t)(seg&1)*HWp;
  int mi=seg*Kk+ki;
  int yci=kyi[mi], xci=kxi[mi];
  for (int i=p;i<PS+1;i+=256){ sat[0][i]=0.0f; sat[i][0]=0.0f; }
  if (p==0) sat[0][PS]=0.0f;
  for (int i=p;i<PS*PS;i+=256){
    int ly=i/PS, lx=i-ly*PS;
    int gy=yci-PR+ly, gx=xci-PR+lx;
    sat[ly+1][lx+1]=(gy>=0&&gy<Hh&&gx>=0&&gx<Ww)?img[(size_t)gy*Ww+gx]:0.0f;
  }
  __syncthreads();
  if (p<PS){
    float run=0.0f;
    for(int x=1;x<=PS;x++){ run+=sat[p+1][x]; sat[p+1][x]=run; }
  }
  __syncthreads();
  if (p<PS){
    float run=0.0f;
    for(int y=1;y<=PS;y++){ run+=sat[y][p+1]; sat[y][p+1]=run; }
  }
  __syncthreads();
  float yc=(float)yci, xc=(float)xci;
  float th=kth[mi];
  float c=cosf(th), s=sinf(th);
  float ox1=offs[p*4+0], oy1=offs[p*4+1], ox2=offs[p*4+2], oy2=offs[p*4+3];
  int r=rad[p];
  float w=WR[r];
  float px1=xc+c*ox1-s*oy1, py1=yc+s*ox1+c*oy1;
  float px2=xc+c*ox2-s*oy2, py2=yc+s*ox2+c*oy2;
  auto boxl=[&](float px,float py,int r_)->float{
    float rx=rintf(px), ry=rintf(py);
    int xi=(int)fminf(fmaxf(rx,0.0f),(float)(Ww-1));
    int yi=(int)fminf(fmaxf(ry,0.0f),(float)(Hh-1));
    int lx=xi-(xci-PR), ly=yi-(yci-PR);
    int y2=ly+r_+1, y1=ly-r_, x2=lx+r_+1, x1=lx-r_;
    return sat[y2][x2]-sat[y1][x2]-sat[y2][x1]+sat[y1][x1];
  };
  float s1=boxl(px1,py1,r)*w;
  float s2=boxl(px2,py2,r)*w;
  float v=(s1-s2-thrv[p])*kval[mi];
  float t=v*v;
  for(int o=32;o;o>>=1) t+=__shfl_down(t,o);
  if((p&63)==0) sm[p>>6]=t;
  __syncthreads();
  if(p==0) nsh=sqrtf(sm[0]+sm[1]+sm[2]+sm[3]);
  __syncthreads();
  float dv=v/(nsh+1e-8f);
  float* dd=(seg<2?d1:d2);
  dd[((size_t)(seg&1)*Kk+ki)*Pp+p]=dv;
  float t2=dv*dv;
  for(int o=32;o;o>>=1) t2+=__shfl_down(t2,o);
  __syncthreads();
  if((p&63)==0) sm[p>>6]=t2;
  __syncthreads();
  if(p==0){ float* sq=(seg<2?sq1:sq2); sq[(size_t)(seg&1)*Kk+ki]=sm[0]+sm[1]+sm[2]+sm[3]; }
}

// ---------------- pairwise distance -> Z (padded stride, and transposed copy) ----------------
__global__ __launch_bounds__(256) void dist_kernel(const float* __restrict__ d1, const float* __restrict__ d2,
                            const float* __restrict__ sq1, const float* __restrict__ sq2,
                            float* __restrict__ Zm, float* __restrict__ Zt){
  int b=blockIdx.z;
  int i0=blockIdx.y*64, j0=blockIdx.x*64;
  int tid=threadIdx.x;
  int tx=tid&15, ty=tid>>4;
  __shared__ float Ast[64][68], Bst[64][68];
  const float* D1=d1+(size_t)b*Kk*Pp;
  const float* D2=d2+(size_t)b*Kk*Pp;
  float acc[4][4]={};
  for(int p0=0;p0<Pp;p0+=64){
    for(int i=tid;i<64*16;i+=256){
      int row=i>>4, c4=(i&15)<<2;
      float4 va=*reinterpret_cast<const float4*>(&D1[(size_t)(i0+row)*Pp+p0+c4]);
      float4 vb=*reinterpret_cast<const float4*>(&D2[(size_t)(j0+row)*Pp+p0+c4]);
      Ast[c4+0][row]=va.x; Ast[c4+1][row]=va.y; Ast[c4+2][row]=va.z; Ast[c4+3][row]=va.w;
      Bst[c4+0][row]=vb.x; Bst[c4+1][row]=vb.y; Bst[c4+2][row]=vb.z; Bst[c4+3][row]=vb.w;
    }
    __syncthreads();
    #pragma unroll 8
    for(int kk=0;kk<64;++kk){
      float4 av=*reinterpret_cast<const float4*>(&Ast[kk][ty*4]);
      float4 bv=*reinterpret_cast<const float4*>(&Bst[kk][tx*4]);
      acc[0][0]=fmaf(av.x,bv.x,acc[0][0]); acc[0][1]=fmaf(av.x,bv.y,acc[0][1]);
      acc[0][2]=fmaf(av.x,bv.z,acc[0][2]); acc[0][3]=fmaf(av.x,bv.w,acc[0][3]);
      acc[1][0]=fmaf(av.y,bv.x,acc[1][0]); acc[1][1]=fmaf(av.y,bv.y,acc[1][1]);
      acc[1][2]=fmaf(av.y,bv.z,acc[1][2]); acc[1][3]=fmaf(av.y,bv.w,acc[1][3]);
      acc[2][0]=fmaf(av.z,bv.x,acc[2][0]); acc[2][1]=fmaf(av.z,bv.y,acc[2][1]);
      acc[2][2]=fmaf(av.z,bv.z,acc[2][2]); acc[2][3]=fmaf(av.z,bv.w,acc[2][3]);
      acc[3][0]=fmaf(av.w,bv.x,acc[3][0]); acc[3][1]=fmaf(av.w,bv.y,acc[3][1]);
      acc[3][2]=fmaf(av.w,bv.z,acc[3][2]); acc[3][3]=fmaf(av.w,bv.w,acc[3][3]);
    }
    __syncthreads();
  }
  int gi=i0+ty*4, gj=j0+tx*4;
  float si[4], sj[4];
  #pragma unroll
  for(int i=0;i<4;i++){ si[i]=sq1[b*Kk+gi+i]; sj[i]=sq2[b*Kk+gj+i]; }
  #pragma unroll
  for(int i=0;i<4;i++){
    #pragma unroll
    for(int j=0;j<4;j++){
      float dd=si[i]+sj[j]-2.0f*acc[i][j];
      float dist=sqrtf(fmaxf(dd,0.0f)+1e-12f);
      Zm[(size_t)b*ZB+(size_t)(gi+i)*ZLD+(gj+j)]=-dist;
      Zt[(size_t)b*ZB+(size_t)(gj+j)*ZLD+(gi+i)]=-dist;
    }
  }
}

// border (=1.0) + pad columns (=-1e30 so exp -> 0)
__global__ void zborder_kernel(float* __restrict__ Zm, float* __restrict__ Zt){
  int i=blockIdx.x*256+threadIdx.x;
  if(i>=Bb*KP1) return;
  int b=i/KP1, j=i-(i/KP1)*KP1;
  size_t base=(size_t)b*ZB;
  Zm[base+(size_t)j*ZLD+Kk]=1.0f;
  Zm[base+(size_t)Kk*ZLD+j]=1.0f;
  Zt[base+(size_t)j*ZLD+Kk]=1.0f;
  Zt[base+(size_t)Kk*ZLD+j]=1.0f;
  for(int c=KP1;c<ZLD;c++){
    Zm[base+(size_t)j*ZLD+c]=-1.0e30f;
    Zt[base+(size_t)j*ZLD+c]=-1.0e30f;
  }
}

// ---------------- precompute E = exp(Z) in fp16 (pads -> 0) ----------------
__global__ void expz_kernel(const float* __restrict__ Zm, const float* __restrict__ Zt,
                            __half* __restrict__ Em, __half* __restrict__ Et){
  size_t q=(size_t)blockIdx.x*256+threadIdx.x;
  const size_t tot4=(size_t)Bb*ZB/4;
  if(q>=2*tot4) return;
  const float* src=(q<tot4)?Zm:Zt;
  __half* dst=(q<tot4)?Em:Et;
  size_t j=(q<tot4)?q:q-tot4;
  float4 z=reinterpret_cast<const float4*>(src)[j];
  __half2 a=__floats2half2_rn(expf(z.x),expf(z.y));
  __half2 b=__floats2half2_rn(expf(z.z),expf(z.w));
  reinterpret_cast<__half2*>(dst)[2*j]=a;
  reinterpret_cast<__half2*>(dst)[2*j+1]=b;
}

// ev = exp(v=0) = 1 on valid cols, 0 on pads; eu zeroed
__global__ void init_euv(float* __restrict__ euv, float* __restrict__ evv){
  int i=blockIdx.x*256+threadIdx.x;
  if(i>=Bb*ZLD) return;
  int j=i-(i/ZLD)*ZLD;
  evv[i]=(j<KP1)?1.0f:0.0f;
  euv[i]=0.0f;
}

// ---------------- Sinkhorn half-iteration as fp16 GEMV: eu = elm / (E @ ev); u = lm - log(s) ----------------
struct H4{ __half2 a, b; };
__global__ __launch_bounds__(256) void sink_gemv(const __half* __restrict__ E,
        const float* __restrict__ evin, float* __restrict__ euout, float* __restrict__ uout){
  int row=blockIdx.x*4+(threadIdx.x>>6);
  if(row>=Bb*KP1) return;
  int b=row/KP1, i=row-b*KP1;
  int lane=threadIdx.x&63;
  const H4* e4=reinterpret_cast<const H4*>(E+((size_t)b*KP1+i)*ZLD);
  const float4* v4=reinterpret_cast<const float4*>(evin+(size_t)b*ZLD);
  float s=0.0f;
  for(int j=lane;j<ZLD/4;j+=64){
    H4 e=e4[j]; float4 v=v4[j];
    float2 ea=__half22float2(e.a), eb=__half22float2(e.b);
    s=fmaf(ea.x,v.x,s); s=fmaf(ea.y,v.y,s);
    s=fmaf(eb.x,v.z,s); s=fmaf(eb.y,v.w,s);
  }
  for(int o=32;o;o>>=1) s+=__shfl_down(s,o);
  if(lane==0){
    float lm,elm;
    if(i<Kk){ lm=NORMV; elm=4.8828125e-4f; }       // exp(-log 2K) = 1/2048 exact
    else    { lm=LOGKV+NORMV; elm=0.5f; }          // K/(2K) exact
    euout[(size_t)b*ZLD+i]=elm/s;
    uout [(size_t)b*ZLD+i]=lm-logf(s);
  }
}

// ---------------- final probs = exp(Z+u+v-norm) ----------------
__global__ void probs_kernel(const float* __restrict__ Zm, const float* __restrict__ uu,
                             const float* __restrict__ vv, float* __restrict__ outp){
  size_t i=(size_t)blockIdx.x*256+threadIdx.x;
  const size_t tot=(size_t)Bb*KP1*KP1;
  if(i>=tot) return;
  size_t b=i/((size_t)KP1*KP1);
  size_t rem=i-b*(size_t)KP1*KP1;
  int rr=(int)(rem/KP1), cc=(int)(rem-(size_t)(rem/KP1)*KP1);
  outp[i]=expf(Zm[b*ZB+(size_t)rr*ZLD+cc]+uu[b*ZLD+rr]+vv[b*ZLD+cc]-NORMV);
}

extern "C" void kernel_launch(void* const* d_in, const int* in_sizes, int n_in,
                              void* d_out, int out_size, void* d_ws, size_t ws_size,
                              hipStream_t stream) {
  (void)in_sizes; (void)n_in; (void)out_size;
  const float* img1=(const float*)d_in[0];
  const float* img2=(const float*)d_in[1];
  const float* offs=(const float*)d_in[2];
  const float* thrv=(const float*)d_in[3];
  const int*   rad =(const int*)d_in[4];
  float* out=(float*)d_out;

  const bool batched = ws_size >= ((size_t)72<<20);
  const int NP = batched ? 4 : 2;
  const size_t PB = HWp*(size_t)NP*4;

  char* wp=(char*)d_ws;
  auto carve=[&](size_t bytes)->char*{ char* p=wp; wp += (bytes+255)&~(size_t)255; return p; };
  float* r0  =(float*)carve(PB);               // L ping / Zm
  float* r1  =(float*)carve(PB);               // L pong / Zt
  float* resp=(float*)carve(PB);               // resp / Em,Et (fp16)
  u64*  lists=(u64*)carve((size_t)NSEG*LISTCAP*8);
  char* stateblk = carve(8192);
  int* cnt     =(int*)(stateblk);              // [seg*64]
  int* selcnt  =(int*)(stateblk+1024);         // [seg*64]
  u64* selbuf  =(u64*)carve((size_t)NSEG*Kk*8);
  int* kyi     =(int*)carve((size_t)NSEG*Kk*4);
  int* kxi     =(int*)carve((size_t)NSEG*Kk*4);
  float* kval  =(float*)carve((size_t)NSEG*Kk*4);
  float* kth   =(float*)carve((size_t)NSEG*Kk*4);
  float* d1    =(float*)carve((size_t)Bb*Kk*Pp*4);
  float* d2    =(float*)carve((size_t)Bb*Kk*Pp*4);
  float* sq1   =(float*)carve((size_t)Bb*Kk*4);
  float* sq2   =(float*)carve((size_t)Bb*Kk*4);
  float* uvec  =(float*)carve((size_t)Bb*ZLD*4);
  float* vvec  =(float*)carve((size_t)Bb*ZLD*4);
  float* euvec =(float*)carve((size_t)Bb*ZLD*4);
  float* evvec =(float*)carve((size_t)Bb*ZLD*4);
  float* wn    =(float*)carve(64);

  const size_t EBYTES = ((size_t)Bb*ZB*2 + 255)&~(size_t)255;
  __half* Em=(__half*)resp;
  __half* Et=(__half*)((char*)resp + EBYTES);

  hipMemsetAsync(stateblk, 0, 8192, stream);
  init_weights<<<1,32,0,stream>>>(wn);

  dim3 TB(32,8);
  if (batched){
    dim3 TG(Ww/32, Hh/32, 4);
    hipMemcpyAsync(r0,       img1, PLn*4, hipMemcpyDeviceToDevice, stream);
    hipMemcpyAsync(r0+2*HWp, img2, PLn*4, hipMemcpyDeviceToDevice, stream);
    float* cur=r0; float* oth=r1;
    for(int st=1; st<=9; ++st){
      fed_step<<<TG,TB,0,stream>>>(cur, oth);
      float* tp=cur; cur=oth; oth=tp;
      if(st%3==0) response_kernel<<<TG,TB,0,stream>>>(cur, resp, st==3);
    }
    detect_compact<<<TG,TB,0,stream>>>(resp, lists, cnt, 0);
  } else {
    dim3 TG(Ww/32, Hh/32, Bb);
    for(int im=0; im<2; ++im){
      const float* srcimg = (im==0)? img1 : img2;
      hipMemcpyAsync(r0, srcimg, PLn*4, hipMemcpyDeviceToDevice, stream);
      float* cur=r0; float* oth=r1;
      for(int st=1; st<=9; ++st){
        fed_step<<<TG,TB,0,stream>>>(cur, oth);
        float* tp=cur; cur=oth; oth=tp;
        if(st%3==0) response_kernel<<<TG,TB,0,stream>>>(cur, resp, st==3);
      }
      detect_compact<<<TG,TB,0,stream>>>(resp, lists, cnt, im*2);
    }
  }

  topk_one<<<dim3(NSEG),dim3(1024),0,stream>>>(lists, cnt, selbuf, selcnt);
  finalize_kernel<<<NSEG,1024,0,stream>>>(selbuf, selcnt, kyi, kxi, kval, out);
  orient_kernel<<<dim3(Kk,NSEG),dim3(64),0,stream>>>(img1, img2, kyi, kxi, wn, kth);
  bad_kernel<<<dim3(Kk,NSEG),dim3(256),0,stream>>>(img1, img2, offs, thrv, rad,
                                                   kyi, kxi, kval, kth, d1, d2, sq1, sq2);

  float* Zm=r0; float* Zt=r1;
  dist_kernel<<<dim3(16,16,Bb),dim3(256),0,stream>>>(d1,d2,sq1,sq2,Zm,Zt);
  zborder_kernel<<<dim3((Bb*KP1+255)/256),dim3(256),0,stream>>>(Zm,Zt);
  {
    size_t tot4=(size_t)Bb*ZB/4;
    expz_kernel<<<dim3((u32)((2*tot4+255)/256)),dim3(256),0,stream>>>(Zm,Zt,Em,Et);
  }
  init_euv<<<dim3((Bb*ZLD+255)/256),dim3(256),0,stream>>>(euvec,evvec);
  for(int it=0; it<20; ++it){
    sink_gemv<<<dim3((Bb*KP1+3)/4),dim3(256),0,stream>>>(Em, evvec, euvec, uvec);
    sink_gemv<<<dim3((Bb*KP1+3)/4),dim3(256),0,stream>>>(Et, euvec, evvec, vvec);
  }
  size_t tot=(size_t)Bb*KP1*KP1;
  probs_kernel<<<dim3((u32)((tot+255)/256)),dim3(256),0,stream>>>(Zm, uvec, vvec, out + (size_t)2*Bb*Kk*2);
}